// Round 3
// baseline (5285.947 us; speedup 1.0000x reference)
//
#include <hip/hip_runtime.h>
#include <cstddef>

using u16 = unsigned short;
using u32 = unsigned int;

// ---------- bf16 helpers ----------
__device__ __forceinline__ u16 f2bf(float f) {
  u32 x = __float_as_uint(f);
  return (u16)((x + 0x7fffu + ((x >> 16) & 1u)) >> 16);  // RNE
}
__device__ __forceinline__ void unpack8(const uint4 u, float* f) {
  f[0] = __uint_as_float(u.x << 16);
  f[1] = __uint_as_float(u.x & 0xffff0000u);
  f[2] = __uint_as_float(u.y << 16);
  f[3] = __uint_as_float(u.y & 0xffff0000u);
  f[4] = __uint_as_float(u.z << 16);
  f[5] = __uint_as_float(u.z & 0xffff0000u);
  f[6] = __uint_as_float(u.w << 16);
  f[7] = __uint_as_float(u.w & 0xffff0000u);
}
__device__ __forceinline__ uint4 pack8(const float* f) {
  uint4 r;
  r.x = ((u32)f2bf(f[0])) | (((u32)f2bf(f[1])) << 16);
  r.y = ((u32)f2bf(f[2])) | (((u32)f2bf(f[3])) << 16);
  r.z = ((u32)f2bf(f[4])) | (((u32)f2bf(f[5])) << 16);
  r.w = ((u32)f2bf(f[6])) | (((u32)f2bf(f[7])) << 16);
  return r;
}

// ---------- GEMM: C[M,N] = epi(A[M,K] @ W[K,N] + bias) ----------
// A: fp32 (AF32) or bf16. W,bias: fp32. C: fp32 (OF32) or bf16.
// EPI: 0 identity, 1 exact GELU. 128x128 tile, BK=32, 256 thr, 8x8/thr.
#define TM 128
#define TN 128
#define TK 32

template<bool AF32, bool OF32, int EPI>
__global__ __launch_bounds__(256, 2) void gemm_bias(
    const void* __restrict__ Av, const float* __restrict__ W,
    const float* __restrict__ bias, void* __restrict__ Cout,
    int M, int N, int K)
{
  __shared__ float As[TK][TM + 4];  // k-major
  __shared__ float Bs[TK][TN + 4];
  const int tid = threadIdx.x;
  const int m0 = blockIdx.y * TM;
  const int n0 = blockIdx.x * TN;
  const int tx = tid & 15, ty = tid >> 4;

  const int ra = tid >> 1;        // A row in tile (0..127)
  const int ka = (tid & 1) * 16;  // 0/16
  const int rb = tid >> 3;        // B k-row (0..31)
  const int nb = (tid & 7) * 16;  // 0..112

  float acc[8][8];
#pragma unroll
  for (int i = 0; i < 8; ++i)
#pragma unroll
    for (int j = 0; j < 8; ++j) acc[i][j] = 0.f;

  const int arow = m0 + ra;
  for (int k0 = 0; k0 < K; k0 += TK) {
    __syncthreads();
    {
      float f[16];
      if (arow < M) {
        if (AF32) {
          const float4* p = reinterpret_cast<const float4*>(
              (const float*)Av + (size_t)arow * K + k0 + ka);
          const float4 a = p[0], b = p[1], c = p[2], d = p[3];
          f[0] = a.x; f[1] = a.y; f[2] = a.z; f[3] = a.w;
          f[4] = b.x; f[5] = b.y; f[6] = b.z; f[7] = b.w;
          f[8] = c.x; f[9] = c.y; f[10] = c.z; f[11] = c.w;
          f[12] = d.x; f[13] = d.y; f[14] = d.z; f[15] = d.w;
        } else {
          const uint4* p = reinterpret_cast<const uint4*>(
              (const u16*)Av + (size_t)arow * K + k0 + ka);
          unpack8(p[0], f); unpack8(p[1], f + 8);
        }
      } else {
#pragma unroll
        for (int j = 0; j < 16; ++j) f[j] = 0.f;
      }
#pragma unroll
      for (int j = 0; j < 16; ++j) As[ka + j][ra] = f[j];
    }
    {
      const float4* p = reinterpret_cast<const float4*>(W + (size_t)(k0 + rb) * N + n0 + nb);
      const float4 a = p[0], b = p[1], c = p[2], d = p[3];
      float* dst = &Bs[rb][nb];
      dst[0] = a.x; dst[1] = a.y; dst[2] = a.z; dst[3] = a.w;
      dst[4] = b.x; dst[5] = b.y; dst[6] = b.z; dst[7] = b.w;
      dst[8] = c.x; dst[9] = c.y; dst[10] = c.z; dst[11] = c.w;
      dst[12] = d.x; dst[13] = d.y; dst[14] = d.z; dst[15] = d.w;
    }
    __syncthreads();
#pragma unroll 8
    for (int kk = 0; kk < TK; ++kk) {
      const float4* ar = reinterpret_cast<const float4*>(&As[kk][0]);
      const float4* br = reinterpret_cast<const float4*>(&Bs[kk][0]);
      const float4 a0 = ar[ty * 2], a1 = ar[ty * 2 + 1];
      const float4 b0 = br[tx * 2], b1 = br[tx * 2 + 1];
      const float av[8] = {a0.x, a0.y, a0.z, a0.w, a1.x, a1.y, a1.z, a1.w};
      const float bv[8] = {b0.x, b0.y, b0.z, b0.w, b1.x, b1.y, b1.z, b1.w};
#pragma unroll
      for (int i = 0; i < 8; ++i)
#pragma unroll
        for (int j = 0; j < 8; ++j) acc[i][j] = fmaf(av[i], bv[j], acc[i][j]);
    }
  }

  float bcol[8];
  {
    const float4* bp = reinterpret_cast<const float4*>(bias + n0 + tx * 8);
    const float4 b0 = bp[0], b1 = bp[1];
    bcol[0] = b0.x; bcol[1] = b0.y; bcol[2] = b0.z; bcol[3] = b0.w;
    bcol[4] = b1.x; bcol[5] = b1.y; bcol[6] = b1.z; bcol[7] = b1.w;
  }
#pragma unroll
  for (int i = 0; i < 8; ++i) {
    const int gr = m0 + ty * 8 + i;
    if (gr >= M) continue;
    float c[8];
#pragma unroll
    for (int j = 0; j < 8; ++j) c[j] = acc[i][j] + bcol[j];
    if (EPI == 1) {
#pragma unroll
      for (int j = 0; j < 8; ++j)
        c[j] = 0.5f * c[j] * (1.0f + erff(c[j] * 0.70710678118654752f));
    }
    if (OF32) {
      float4* out = reinterpret_cast<float4*>((float*)Cout + (size_t)gr * N + n0 + tx * 8);
      out[0] = make_float4(c[0], c[1], c[2], c[3]);
      out[1] = make_float4(c[4], c[5], c[6], c[7]);
    } else {
      *reinterpret_cast<uint4*>((u16*)Cout + (size_t)gr * N + n0 + tx * 8) = pack8(c);
    }
  }
}

// ---------- self-attention (flash-style, band mask ADDS +1.0 in-band) ----------
// Q,K,V,CTX internal bf16. grid (S/32, NH, B), 256 threads.
__global__ __launch_bounds__(256, 2) void attn_self(
    const u16* __restrict__ Q, const u16* __restrict__ K,
    const u16* __restrict__ V, u16* __restrict__ CTX,
    const int* __restrict__ rngp)
{
  const int S = 2048, H = 1024;
  const int qt = blockIdx.x, h = blockIdx.y, b = blockIdx.z;
  const int range = rngp[0];
  const int tid = threadIdx.x;
  const int r = tid >> 3, j = tid & 7;
  __shared__ float qs[32][68], ks[32][68], vs[32][68];
  __shared__ float pc[32][36];

  const int qrow = qt * 32 + r;
  {
    const uint4* qp = reinterpret_cast<const uint4*>(Q + ((size_t)(b * S + qrow) * H + h * 64 + j * 8));
    float f[8]; unpack8(qp[0], f);
#pragma unroll
    for (int d = 0; d < 8; ++d) qs[r][j * 8 + d] = f[d];
  }
  float m = -1e30f, l = 0.f;
  float acc[8] = {0, 0, 0, 0, 0, 0, 0, 0};

  for (int c = 0; c < 64; ++c) {
    __syncthreads();
    {
      const int krow = c * 32 + r;
      const size_t base = (size_t)(b * S + krow) * H + h * 64 + j * 8;
      float f[8];
      unpack8(reinterpret_cast<const uint4*>(K + base)[0], f);
#pragma unroll
      for (int d = 0; d < 8; ++d) ks[r][j * 8 + d] = f[d];
      unpack8(reinterpret_cast<const uint4*>(V + base)[0], f);
#pragma unroll
      for (int d = 0; d < 8; ++d) vs[r][j * 8 + d] = f[d];
    }
    __syncthreads();

    float s[4] = {0, 0, 0, 0};
    const float4* qr4 = reinterpret_cast<const float4*>(&qs[r][0]);
#pragma unroll 4
    for (int d4 = 0; d4 < 16; ++d4) {
      const float4 qv = qr4[d4];
#pragma unroll
      for (int cc = 0; cc < 4; ++cc) {
        const float4 kv = reinterpret_cast<const float4*>(&ks[j + cc * 8][0])[d4];
        s[cc] += qv.x * kv.x + qv.y * kv.y + qv.z * kv.z + qv.w * kv.w;
      }
    }
    float rmax = -1e30f;
#pragma unroll
    for (int cc = 0; cc < 4; ++cc) {
      const int kcol = c * 32 + j + cc * 8;
      int dd = qrow - kcol; if (dd < 0) dd = -dd;
      s[cc] = s[cc] * 0.125f + ((dd <= range) ? 1.0f : 0.0f);
      rmax = fmaxf(rmax, s[cc]);
    }
    rmax = fmaxf(rmax, __shfl_xor(rmax, 1));
    rmax = fmaxf(rmax, __shfl_xor(rmax, 2));
    rmax = fmaxf(rmax, __shfl_xor(rmax, 4));
    const float newm = fmaxf(m, rmax);
    const float corr = expf(m - newm);
    float rsum = 0.f;
#pragma unroll
    for (int cc = 0; cc < 4; ++cc) {
      const float e = expf(s[cc] - newm);
      pc[r][j + cc * 8] = e;
      rsum += e;
    }
    rsum += __shfl_xor(rsum, 1);
    rsum += __shfl_xor(rsum, 2);
    rsum += __shfl_xor(rsum, 4);
    l = l * corr + rsum;
    m = newm;
#pragma unroll
    for (int d = 0; d < 8; ++d) acc[d] *= corr;
#pragma unroll 8
    for (int k2 = 0; k2 < 32; ++k2) {
      const float p = pc[r][k2];
      const float4* vr = reinterpret_cast<const float4*>(&vs[k2][0]);
      const float4 v0 = vr[j * 2], v1 = vr[j * 2 + 1];
      acc[0] = fmaf(p, v0.x, acc[0]); acc[1] = fmaf(p, v0.y, acc[1]);
      acc[2] = fmaf(p, v0.z, acc[2]); acc[3] = fmaf(p, v0.w, acc[3]);
      acc[4] = fmaf(p, v1.x, acc[4]); acc[5] = fmaf(p, v1.y, acc[5]);
      acc[6] = fmaf(p, v1.z, acc[6]); acc[7] = fmaf(p, v1.w, acc[7]);
    }
  }
  const float inv = 1.f / l;
  float o[8];
#pragma unroll
  for (int d = 0; d < 8; ++d) o[d] = acc[d] * inv;
  *reinterpret_cast<uint4*>(CTX + ((size_t)(b * S + qrow) * H + h * 64 + j * 8)) = pack8(o);
}

// ---------- cross-attention (T=50 keys, no mask), bf16 I/O ----------
__global__ __launch_bounds__(256, 1) void attn_cross(
    const u16* __restrict__ Q, const u16* __restrict__ KT,
    const u16* __restrict__ VT, u16* __restrict__ CTX)
{
  const int S = 2048, H = 1024, T = 50;
  const int qt = blockIdx.x, h = blockIdx.y, b = blockIdx.z;
  const int tid = threadIdx.x;
  const int r = tid >> 2, j = tid & 3;
  __shared__ float kt[50][68], vt[50][68];
  __shared__ float qs[64][68];
  __shared__ float ps[64][52];

  for (int idx = tid; idx < T * 8; idx += 256) {
    const int row = idx >> 3, seg = idx & 7;
    float f[8];
    unpack8(reinterpret_cast<const uint4*>(KT + (size_t)row * H + h * 64 + seg * 8)[0], f);
#pragma unroll
    for (int d = 0; d < 8; ++d) kt[row][seg * 8 + d] = f[d];
    unpack8(reinterpret_cast<const uint4*>(VT + (size_t)row * H + h * 64 + seg * 8)[0], f);
#pragma unroll
    for (int d = 0; d < 8; ++d) vt[row][seg * 8 + d] = f[d];
  }
  const int qrow = qt * 64 + r;
  {
    const uint4* qp = reinterpret_cast<const uint4*>(Q + ((size_t)(b * S + qrow) * H + h * 64 + j * 16));
    float f[16];
    unpack8(qp[0], f); unpack8(qp[1], f + 8);
#pragma unroll
    for (int d = 0; d < 16; ++d) qs[r][j * 16 + d] = f[d];
  }
  __syncthreads();

  float sreg[13];
  float rmax = -1e30f;
#pragma unroll
  for (int i = 0; i < 13; ++i) {
    const int k = j + 4 * i;
    float s = -1e30f;
    if (k < T) {
      float acc = 0.f;
      const float4* qr4 = reinterpret_cast<const float4*>(&qs[r][0]);
      const float4* kr4 = reinterpret_cast<const float4*>(&kt[k][0]);
#pragma unroll
      for (int d4 = 0; d4 < 16; ++d4) {
        const float4 qv = qr4[d4], kv = kr4[d4];
        acc += qv.x * kv.x + qv.y * kv.y + qv.z * kv.z + qv.w * kv.w;
      }
      s = acc * 0.125f;
    }
    sreg[i] = s;
    rmax = fmaxf(rmax, s);
  }
  rmax = fmaxf(rmax, __shfl_xor(rmax, 1));
  rmax = fmaxf(rmax, __shfl_xor(rmax, 2));
  float rsum = 0.f;
#pragma unroll
  for (int i = 0; i < 13; ++i) {
    const int k = j + 4 * i;
    if (k < T) {
      const float e = expf(sreg[i] - rmax);
      ps[r][k] = e;
      rsum += e;
    }
  }
  rsum += __shfl_xor(rsum, 1);
  rsum += __shfl_xor(rsum, 2);
  const float inv = 1.f / rsum;

  float acc[16];
#pragma unroll
  for (int d = 0; d < 16; ++d) acc[d] = 0.f;
  for (int k = 0; k < T; ++k) {
    const float p = ps[r][k];
    const float4* vr4 = reinterpret_cast<const float4*>(&vt[k][0]);
#pragma unroll
    for (int q4 = 0; q4 < 4; ++q4) {
      const float4 v = vr4[j * 4 + q4];
      acc[q4 * 4 + 0] = fmaf(p, v.x, acc[q4 * 4 + 0]);
      acc[q4 * 4 + 1] = fmaf(p, v.y, acc[q4 * 4 + 1]);
      acc[q4 * 4 + 2] = fmaf(p, v.z, acc[q4 * 4 + 2]);
      acc[q4 * 4 + 3] = fmaf(p, v.w, acc[q4 * 4 + 3]);
    }
  }
  float o[16];
#pragma unroll
  for (int d = 0; d < 16; ++d) o[d] = acc[d] * inv;
  u16* dst = CTX + ((size_t)(b * S + qrow) * H + h * 64 + j * 16);
  reinterpret_cast<uint4*>(dst)[0] = pack8(o);
  reinterpret_cast<uint4*>(dst)[1] = pack8(o + 8);
}

// ---------- residual + LayerNorm: out = LN(C + Res)*g + b ----------
// C/Res/Out dtype per template. g,b fp32.
template<bool CF32, bool RF32, bool OF32>
__global__ __launch_bounds__(256) void ln_res(
    const void* __restrict__ C, const void* __restrict__ Res,
    const float* __restrict__ G, const float* __restrict__ Bb,
    void* __restrict__ Out)
{
  const int H = 1024;
  const int row = blockIdx.x;
  const int tid = threadIdx.x;
  float x[4];
  {
    float c4[4], r4[4];
    if (CF32) {
      const float4 c = reinterpret_cast<const float4*>((const float*)C + (size_t)row * H)[tid];
      c4[0] = c.x; c4[1] = c.y; c4[2] = c.z; c4[3] = c.w;
    } else {
      const uint2 cu = reinterpret_cast<const uint2*>((const u16*)C + (size_t)row * H)[tid];
      c4[0] = __uint_as_float(cu.x << 16); c4[1] = __uint_as_float(cu.x & 0xffff0000u);
      c4[2] = __uint_as_float(cu.y << 16); c4[3] = __uint_as_float(cu.y & 0xffff0000u);
    }
    if (RF32) {
      const float4 rr = reinterpret_cast<const float4*>((const float*)Res + (size_t)row * H)[tid];
      r4[0] = rr.x; r4[1] = rr.y; r4[2] = rr.z; r4[3] = rr.w;
    } else {
      const uint2 ru = reinterpret_cast<const uint2*>((const u16*)Res + (size_t)row * H)[tid];
      r4[0] = __uint_as_float(ru.x << 16); r4[1] = __uint_as_float(ru.x & 0xffff0000u);
      r4[2] = __uint_as_float(ru.y << 16); r4[3] = __uint_as_float(ru.y & 0xffff0000u);
    }
#pragma unroll
    for (int i = 0; i < 4; ++i) x[i] = c4[i] + r4[i];
  }
  float s = x[0] + x[1] + x[2] + x[3];
  float q = x[0] * x[0] + x[1] * x[1] + x[2] * x[2] + x[3] * x[3];
#pragma unroll
  for (int off = 1; off < 64; off <<= 1) {
    s += __shfl_xor(s, off);
    q += __shfl_xor(q, off);
  }
  __shared__ float sb[4][2];
  const int wid = tid >> 6;
  if ((tid & 63) == 0) { sb[wid][0] = s; sb[wid][1] = q; }
  __syncthreads();
  s = sb[0][0] + sb[1][0] + sb[2][0] + sb[3][0];
  q = sb[0][1] + sb[1][1] + sb[2][1] + sb[3][1];
  const float mean = s * (1.f / 1024.f);
  const float var = q * (1.f / 1024.f) - mean * mean;
  const float rstd = rsqrtf(fmaxf(var, 0.f) + 1e-12f);
  const float4 g4 = reinterpret_cast<const float4*>(G)[tid];
  const float4 b4 = reinterpret_cast<const float4*>(Bb)[tid];
  const float g[4] = {g4.x, g4.y, g4.z, g4.w};
  const float bb[4] = {b4.x, b4.y, b4.z, b4.w};
  float o[4];
#pragma unroll
  for (int i = 0; i < 4; ++i) o[i] = (x[i] - mean) * rstd * g[i] + bb[i];
  if (OF32) {
    reinterpret_cast<float4*>((float*)Out + (size_t)row * H)[tid] =
        make_float4(o[0], o[1], o[2], o[3]);
  } else {
    uint2 pk;
    pk.x = ((u32)f2bf(o[0])) | (((u32)f2bf(o[1])) << 16);
    pk.y = ((u32)f2bf(o[2])) | (((u32)f2bf(o[3])) << 16);
    reinterpret_cast<uint2*>((u16*)Out + (size_t)row * H)[tid] = pk;
  }
}

// ---------- tag gather: tags[t] = bf16(emb_table[ent_ids[t]]) ----------
__global__ void gather_tags(const float* __restrict__ emb, const int* __restrict__ ids,
                            u16* __restrict__ tags)
{
  const int t = blockIdx.x;
  const int id = ids[t];
  const float4* src = reinterpret_cast<const float4*>(emb + (size_t)id * 1024);
  const float4 a = src[threadIdx.x * 2], b = src[threadIdx.x * 2 + 1];
  const float f[8] = {a.x, a.y, a.z, a.w, b.x, b.y, b.z, b.w};
  reinterpret_cast<uint4*>(tags + (size_t)t * 1024)[threadIdx.x] = pack8(f);
}

// ---------- host ----------
extern "C" void kernel_launch(void* const* d_in, const int* in_sizes, int n_in,
                              void* d_out, int out_size, void* d_ws, size_t ws_size,
                              hipStream_t stream)
{
  const int B = 4, S = 2048, H = 1024, FFN = 4096, T = 50;
  const int M = B * S;

  const bool dict_order = (in_sizes[10] == H * H);
  int i_cqw, i_cqb, i_ckw, i_ckb, i_cvw, i_cvb, i_cow, i_cob;
  int i_slng, i_slnb, i_clng, i_clnb, i_olng, i_olnb;
  int i_iw, i_ib, i_ow, i_ob;
  if (dict_order) {
    i_cqw = 10; i_cqb = 11; i_ckw = 12; i_ckb = 13; i_cvw = 14; i_cvb = 15; i_cow = 16; i_cob = 17;
    i_slng = 18; i_slnb = 19; i_clng = 20; i_clnb = 21; i_olng = 22; i_olnb = 23;
    i_iw = 24; i_ib = 25; i_ow = 26; i_ob = 27;
  } else {
    i_slng = 10; i_slnb = 11;
    i_cqw = 12; i_cqb = 13; i_ckw = 14; i_ckb = 15; i_cvw = 16; i_cvb = 17; i_cow = 18; i_cob = 19;
    i_clng = 20; i_clnb = 21;
    i_iw = 22; i_ib = 23; i_ow = 24; i_ob = 25; i_olng = 26; i_olnb = 27;
  }
  const float* X    = (const float*)d_in[0];
  const float* EMB  = (const float*)d_in[1];
  const float* SQW  = (const float*)d_in[2];
  const float* SQB  = (const float*)d_in[3];
  const float* SKW  = (const float*)d_in[4];
  const float* SKB  = (const float*)d_in[5];
  const float* SVW  = (const float*)d_in[6];
  const float* SVB  = (const float*)d_in[7];
  const float* SOW  = (const float*)d_in[8];
  const float* SOB  = (const float*)d_in[9];
  const float* CQW  = (const float*)d_in[i_cqw];
  const float* CQB  = (const float*)d_in[i_cqb];
  const float* CKW  = (const float*)d_in[i_ckw];
  const float* CKB  = (const float*)d_in[i_ckb];
  const float* CVW  = (const float*)d_in[i_cvw];
  const float* CVB  = (const float*)d_in[i_cvb];
  const float* COW  = (const float*)d_in[i_cow];
  const float* COB  = (const float*)d_in[i_cob];
  const float* SLNG = (const float*)d_in[i_slng];
  const float* SLNB = (const float*)d_in[i_slnb];
  const float* CLNG = (const float*)d_in[i_clng];
  const float* CLNB = (const float*)d_in[i_clnb];
  const float* OLNG = (const float*)d_in[i_olng];
  const float* OLNB = (const float*)d_in[i_olnb];
  const float* IW   = (const float*)d_in[i_iw];
  const float* IB   = (const float*)d_in[i_ib];
  const float* OW   = (const float*)d_in[i_ow];
  const float* OB   = (const float*)d_in[i_ob];
  const int* IDS  = (const int*)d_in[28];
  const int* RNG  = (const int*)d_in[29];

  // workspace: small bufs (bf16) then 5 bf16 activation slots; ~84.5 MB total.
  char* ws = (char*)d_ws;
  u16* tags = (u16*)(ws);                    // 100 KB
  u16* ktb  = (u16*)(ws + (1 << 17));        // 100 KB
  u16* vtb  = (u16*)(ws + (2 << 17));        // 100 KB
  const size_t SZ = (size_t)M * H * 2;       // 16.78 MB
  char* slots = ws + (4 << 17);
  u16* s0 = (u16*)(slots);
  u16* s1 = (u16*)(slots + SZ);
  u16* s2 = (u16*)(slots + 2 * SZ);
  u16* s3 = (u16*)(slots + 3 * SZ);
  u16* s4 = (u16*)(slots + 4 * SZ);
  u16* inter = s0;                           // M x FFN bf16 spans s0..s3
  float* outp = (float*)d_out;

  const dim3 blk(256);
  const dim3 gsq(H / TN, M / TM);

  // --- self-attention block ---
  gemm_bias<true, false, 0><<<gsq, blk, 0, stream>>>(X, SQW, SQB, s0, M, H, H);   // q
  gemm_bias<true, false, 0><<<gsq, blk, 0, stream>>>(X, SKW, SKB, s1, M, H, H);   // k
  gemm_bias<true, false, 0><<<gsq, blk, 0, stream>>>(X, SVW, SVB, s2, M, H, H);   // v
  attn_self<<<dim3(S / 32, 16, B), blk, 0, stream>>>(s0, s1, s2, s3, RNG);
  gemm_bias<false, false, 0><<<gsq, blk, 0, stream>>>(s3, SOW, SOB, s4, M, H, H); // so_out
  ln_res<false, true, false><<<dim3(M), blk, 0, stream>>>(s4, X, SLNG, SLNB, s3); // a1 -> s3

  // --- cross-attention block ---
  gather_tags<<<dim3(T), dim3(128), 0, stream>>>(EMB, IDS, tags);
  gemm_bias<false, false, 0><<<dim3(H / TN, 1), blk, 0, stream>>>(tags, CKW, CKB, ktb, T, H, H);
  gemm_bias<false, false, 0><<<dim3(H / TN, 1), blk, 0, stream>>>(tags, CVW, CVB, vtb, T, H, H);
  gemm_bias<false, false, 0><<<gsq, blk, 0, stream>>>(s3, CQW, CQB, s0, M, H, H); // cq
  attn_cross<<<dim3(S / 64, 16, B), blk, 0, stream>>>(s0, ktb, vtb, s1);          // cctx
  gemm_bias<false, false, 0><<<gsq, blk, 0, stream>>>(s1, COW, COB, s2, M, H, H); // co_out
  ln_res<false, false, false><<<dim3(M), blk, 0, stream>>>(s2, s3, CLNG, CLNB, s4); // a2 -> s4

  // --- FFN block ---
  gemm_bias<false, false, 1><<<dim3(FFN / TN, M / TM), blk, 0, stream>>>(s4, IW, IB, inter, M, FFN, H);
  gemm_bias<false, true, 0><<<gsq, blk, 0, stream>>>(inter, OW, OB, outp, M, H, FFN); // -> d_out (f32 staging)
  ln_res<true, false, true><<<dim3(M), blk, 0, stream>>>(outp, s4, OLNG, OLNB, outp); // in-place final LN
}

// Round 4
// 2892.863 us; speedup vs baseline: 1.8272x; 1.8272x over previous
//
#include <hip/hip_runtime.h>
#include <cstddef>

using u16 = unsigned short;
using u32 = unsigned int;
typedef short bf16x8 __attribute__((ext_vector_type(8)));
typedef float f32x4 __attribute__((ext_vector_type(4)));

// ---------- bf16 helpers ----------
__device__ __forceinline__ u16 f2bf(float f) {
  u32 x = __float_as_uint(f);
  return (u16)((x + 0x7fffu + ((x >> 16) & 1u)) >> 16);  // RNE
}
__device__ __forceinline__ void unpack8(const uint4 u, float* f) {
  f[0] = __uint_as_float(u.x << 16);
  f[1] = __uint_as_float(u.x & 0xffff0000u);
  f[2] = __uint_as_float(u.y << 16);
  f[3] = __uint_as_float(u.y & 0xffff0000u);
  f[4] = __uint_as_float(u.z << 16);
  f[5] = __uint_as_float(u.z & 0xffff0000u);
  f[6] = __uint_as_float(u.w << 16);
  f[7] = __uint_as_float(u.w & 0xffff0000u);
}
__device__ __forceinline__ uint4 pack8(const float* f) {
  uint4 r;
  r.x = ((u32)f2bf(f[0])) | (((u32)f2bf(f[1])) << 16);
  r.y = ((u32)f2bf(f[2])) | (((u32)f2bf(f[3])) << 16);
  r.z = ((u32)f2bf(f[4])) | (((u32)f2bf(f[5])) << 16);
  r.w = ((u32)f2bf(f[6])) | (((u32)f2bf(f[7])) << 16);
  return r;
}

// ---------- MFMA GEMM: C[M,N] = epi(A[M,K] @ Wt[N,K]^T + bias) ----------
// A bf16 [M][K], Wt bf16 [N][K] (pre-transposed), bias fp32.
// OUT: 0 bf16, 1 gelu->bf16, 2 f32. 128x128 tile, BK=32, 256 thr (4 waves),
// wave -> 64x64 subtile (4x4 fragments of 16x16x32 MFMA).
__global__ __launch_bounds__(256, 2) void gemm_mfma_k(
    const u16* __restrict__ A, const u16* __restrict__ Wt,
    const float* __restrict__ bias, void* __restrict__ Cout,
    int M, int N, int K, int outmode)
{
  __shared__ u16 As[128][40];  // 80B row stride: 16B aligned, ~2-way banks
  __shared__ u16 Bs[128][40];
  const int tid = threadIdx.x;
  const int wave = tid >> 6, lane = tid & 63;
  const int wr = wave >> 1, wc = wave & 1;
  const int m0 = blockIdx.y * 128, n0 = blockIdx.x * 128;
  const int lrow = lane & 15, lk = lane >> 4;

  f32x4 acc[4][4];
#pragma unroll
  for (int i = 0; i < 4; ++i)
#pragma unroll
    for (int j = 0; j < 4; ++j) {
      acc[i][j][0] = 0.f; acc[i][j][1] = 0.f; acc[i][j][2] = 0.f; acc[i][j][3] = 0.f;
    }

  const int sr = tid >> 2;         // 0..63
  const int sk = (tid & 3) * 8;    // u16 offset 0/8/16/24
  const bool arow_ok0 = (m0 + sr) < M;
  const bool arow_ok1 = (m0 + sr + 64) < M;

  for (int k0 = 0; k0 < K; k0 += 32) {
    __syncthreads();
    if (arow_ok0)
      *(uint4*)&As[sr][sk] = *(const uint4*)&A[(size_t)(m0 + sr) * K + k0 + sk];
    if (arow_ok1)
      *(uint4*)&As[sr + 64][sk] = *(const uint4*)&A[(size_t)(m0 + sr + 64) * K + k0 + sk];
    *(uint4*)&Bs[sr][sk] = *(const uint4*)&Wt[(size_t)(n0 + sr) * K + k0 + sk];
    *(uint4*)&Bs[sr + 64][sk] = *(const uint4*)&Wt[(size_t)(n0 + sr + 64) * K + k0 + sk];
    __syncthreads();

    bf16x8 af[4], bf[4];
#pragma unroll
    for (int i = 0; i < 4; ++i) {
      af[i] = *(const bf16x8*)&As[wr * 64 + i * 16 + lrow][lk * 8];
      bf[i] = *(const bf16x8*)&Bs[wc * 64 + i * 16 + lrow][lk * 8];
    }
#pragma unroll
    for (int i = 0; i < 4; ++i)
#pragma unroll
      for (int j = 0; j < 4; ++j)
        acc[i][j] = __builtin_amdgcn_mfma_f32_16x16x32_bf16(af[i], bf[j], acc[i][j], 0, 0, 0);
  }

  // epilogue: C/D layout col=lane&15, row=(lane>>4)*4+reg
#pragma unroll
  for (int j = 0; j < 4; ++j) {
    const int gcol = n0 + wc * 64 + j * 16 + lrow;
    const float bj = bias[gcol];
#pragma unroll
    for (int i = 0; i < 4; ++i) {
      const int rbase = m0 + wr * 64 + i * 16 + lk * 4;
#pragma unroll
      for (int reg = 0; reg < 4; ++reg) {
        const int grow = rbase + reg;
        if (grow >= M) continue;
        float c = acc[i][j][reg] + bj;
        if (outmode == 1) c = 0.5f * c * (1.0f + erff(c * 0.70710678118654752f));
        if (outmode == 2)
          ((float*)Cout)[(size_t)grow * N + gcol] = c;
        else
          ((u16*)Cout)[(size_t)grow * N + gcol] = f2bf(c);
      }
    }
  }
}

// ---------- weight transpose+convert: Wt[N][K] bf16 from W[K][N] fp32 ----------
__global__ __launch_bounds__(256) void transpose_conv(
    const float* __restrict__ W, u16* __restrict__ Wt, int K, int N)
{
  __shared__ float t[32][33];
  const int kb = blockIdx.y * 32, nb = blockIdx.x * 32;
  const int x = threadIdx.x & 31;
  const int y4 = (threadIdx.x >> 5) * 4;
#pragma unroll
  for (int i = 0; i < 4; ++i)
    t[y4 + i][x] = W[(size_t)(kb + y4 + i) * N + nb + x];
  __syncthreads();
#pragma unroll
  for (int i = 0; i < 4; ++i)
    Wt[(size_t)(nb + y4 + i) * K + kb + x] = f2bf(t[x][y4 + i]);
}

// ---------- elementwise fp32 -> bf16 ----------
__global__ __launch_bounds__(256) void conv_bf16(
    const float* __restrict__ in, u16* __restrict__ out, int n4)
{
  const int idx = blockIdx.x * 256 + threadIdx.x;
  if (idx >= n4) return;
  const float4 v = reinterpret_cast<const float4*>(in)[idx];
  const float f[4] = {v.x, v.y, v.z, v.w};
  uint2 pk;
  pk.x = ((u32)f2bf(f[0])) | (((u32)f2bf(f[1])) << 16);
  pk.y = ((u32)f2bf(f[2])) | (((u32)f2bf(f[3])) << 16);
  reinterpret_cast<uint2*>(out)[idx] = pk;
}

// ---------- self-attention (flash-style, band mask ADDS +1.0 in-band) ----------
__global__ __launch_bounds__(256, 2) void attn_self(
    const u16* __restrict__ Q, const u16* __restrict__ K,
    const u16* __restrict__ V, u16* __restrict__ CTX,
    const int* __restrict__ rngp)
{
  const int S = 2048, H = 1024;
  const int qt = blockIdx.x, h = blockIdx.y, b = blockIdx.z;
  const int range = rngp[0];
  const int tid = threadIdx.x;
  const int r = tid >> 3, j = tid & 7;
  __shared__ float qs[32][68], ks[32][68], vs[32][68];
  __shared__ float pc[32][36];

  const int qrow = qt * 32 + r;
  {
    const uint4* qp = reinterpret_cast<const uint4*>(Q + ((size_t)(b * S + qrow) * H + h * 64 + j * 8));
    float f[8]; unpack8(qp[0], f);
#pragma unroll
    for (int d = 0; d < 8; ++d) qs[r][j * 8 + d] = f[d];
  }
  float m = -1e30f, l = 0.f;
  float acc[8] = {0, 0, 0, 0, 0, 0, 0, 0};

  for (int c = 0; c < 64; ++c) {
    __syncthreads();
    {
      const int krow = c * 32 + r;
      const size_t base = (size_t)(b * S + krow) * H + h * 64 + j * 8;
      float f[8];
      unpack8(reinterpret_cast<const uint4*>(K + base)[0], f);
#pragma unroll
      for (int d = 0; d < 8; ++d) ks[r][j * 8 + d] = f[d];
      unpack8(reinterpret_cast<const uint4*>(V + base)[0], f);
#pragma unroll
      for (int d = 0; d < 8; ++d) vs[r][j * 8 + d] = f[d];
    }
    __syncthreads();

    float s[4] = {0, 0, 0, 0};
    const float4* qr4 = reinterpret_cast<const float4*>(&qs[r][0]);
#pragma unroll 4
    for (int d4 = 0; d4 < 16; ++d4) {
      const float4 qv = qr4[d4];
#pragma unroll
      for (int cc = 0; cc < 4; ++cc) {
        const float4 kv = reinterpret_cast<const float4*>(&ks[j + cc * 8][0])[d4];
        s[cc] += qv.x * kv.x + qv.y * kv.y + qv.z * kv.z + qv.w * kv.w;
      }
    }
    float rmax = -1e30f;
#pragma unroll
    for (int cc = 0; cc < 4; ++cc) {
      const int kcol = c * 32 + j + cc * 8;
      int dd = qrow - kcol; if (dd < 0) dd = -dd;
      s[cc] = s[cc] * 0.125f + ((dd <= range) ? 1.0f : 0.0f);
      rmax = fmaxf(rmax, s[cc]);
    }
    rmax = fmaxf(rmax, __shfl_xor(rmax, 1));
    rmax = fmaxf(rmax, __shfl_xor(rmax, 2));
    rmax = fmaxf(rmax, __shfl_xor(rmax, 4));
    const float newm = fmaxf(m, rmax);
    const float corr = expf(m - newm);
    float rsum = 0.f;
#pragma unroll
    for (int cc = 0; cc < 4; ++cc) {
      const float e = expf(s[cc] - newm);
      pc[r][j + cc * 8] = e;
      rsum += e;
    }
    rsum += __shfl_xor(rsum, 1);
    rsum += __shfl_xor(rsum, 2);
    rsum += __shfl_xor(rsum, 4);
    l = l * corr + rsum;
    m = newm;
#pragma unroll
    for (int d = 0; d < 8; ++d) acc[d] *= corr;
#pragma unroll 8
    for (int k2 = 0; k2 < 32; ++k2) {
      const float p = pc[r][k2];
      const float4* vr = reinterpret_cast<const float4*>(&vs[k2][0]);
      const float4 v0 = vr[j * 2], v1 = vr[j * 2 + 1];
      acc[0] = fmaf(p, v0.x, acc[0]); acc[1] = fmaf(p, v0.y, acc[1]);
      acc[2] = fmaf(p, v0.z, acc[2]); acc[3] = fmaf(p, v0.w, acc[3]);
      acc[4] = fmaf(p, v1.x, acc[4]); acc[5] = fmaf(p, v1.y, acc[5]);
      acc[6] = fmaf(p, v1.z, acc[6]); acc[7] = fmaf(p, v1.w, acc[7]);
    }
  }
  const float inv = 1.f / l;
  float o[8];
#pragma unroll
  for (int d = 0; d < 8; ++d) o[d] = acc[d] * inv;
  *reinterpret_cast<uint4*>(CTX + ((size_t)(b * S + qrow) * H + h * 64 + j * 8)) = pack8(o);
}

// ---------- cross-attention (T=50 keys, no mask), bf16 I/O ----------
__global__ __launch_bounds__(256, 1) void attn_cross(
    const u16* __restrict__ Q, const u16* __restrict__ KT,
    const u16* __restrict__ VT, u16* __restrict__ CTX)
{
  const int S = 2048, H = 1024, T = 50;
  const int qt = blockIdx.x, h = blockIdx.y, b = blockIdx.z;
  const int tid = threadIdx.x;
  const int r = tid >> 2, j = tid & 3;
  __shared__ float kt[50][68], vt[50][68];
  __shared__ float qs[64][68];
  __shared__ float ps[64][52];

  for (int idx = tid; idx < T * 8; idx += 256) {
    const int row = idx >> 3, seg = idx & 7;
    float f[8];
    unpack8(reinterpret_cast<const uint4*>(KT + (size_t)row * H + h * 64 + seg * 8)[0], f);
#pragma unroll
    for (int d = 0; d < 8; ++d) kt[row][seg * 8 + d] = f[d];
    unpack8(reinterpret_cast<const uint4*>(VT + (size_t)row * H + h * 64 + seg * 8)[0], f);
#pragma unroll
    for (int d = 0; d < 8; ++d) vt[row][seg * 8 + d] = f[d];
  }
  const int qrow = qt * 64 + r;
  {
    const uint4* qp = reinterpret_cast<const uint4*>(Q + ((size_t)(b * S + qrow) * H + h * 64 + j * 16));
    float f[16];
    unpack8(qp[0], f); unpack8(qp[1], f + 8);
#pragma unroll
    for (int d = 0; d < 16; ++d) qs[r][j * 16 + d] = f[d];
  }
  __syncthreads();

  float sreg[13];
  float rmax = -1e30f;
#pragma unroll
  for (int i = 0; i < 13; ++i) {
    const int k = j + 4 * i;
    float s = -1e30f;
    if (k < T) {
      float acc = 0.f;
      const float4* qr4 = reinterpret_cast<const float4*>(&qs[r][0]);
      const float4* kr4 = reinterpret_cast<const float4*>(&kt[k][0]);
#pragma unroll
      for (int d4 = 0; d4 < 16; ++d4) {
        const float4 qv = qr4[d4], kv = kr4[d4];
        acc += qv.x * kv.x + qv.y * kv.y + qv.z * kv.z + qv.w * kv.w;
      }
      s = acc * 0.125f;
    }
    sreg[i] = s;
    rmax = fmaxf(rmax, s);
  }
  rmax = fmaxf(rmax, __shfl_xor(rmax, 1));
  rmax = fmaxf(rmax, __shfl_xor(rmax, 2));
  float rsum = 0.f;
#pragma unroll
  for (int i = 0; i < 13; ++i) {
    const int k = j + 4 * i;
    if (k < T) {
      const float e = expf(sreg[i] - rmax);
      ps[r][k] = e;
      rsum += e;
    }
  }
  rsum += __shfl_xor(rsum, 1);
  rsum += __shfl_xor(rsum, 2);
  const float inv = 1.f / rsum;

  float acc[16];
#pragma unroll
  for (int d = 0; d < 16; ++d) acc[d] = 0.f;
  for (int k = 0; k < T; ++k) {
    const float p = ps[r][k];
    const float4* vr4 = reinterpret_cast<const float4*>(&vt[k][0]);
#pragma unroll
    for (int q4 = 0; q4 < 4; ++q4) {
      const float4 v = vr4[j * 4 + q4];
      acc[q4 * 4 + 0] = fmaf(p, v.x, acc[q4 * 4 + 0]);
      acc[q4 * 4 + 1] = fmaf(p, v.y, acc[q4 * 4 + 1]);
      acc[q4 * 4 + 2] = fmaf(p, v.z, acc[q4 * 4 + 2]);
      acc[q4 * 4 + 3] = fmaf(p, v.w, acc[q4 * 4 + 3]);
    }
  }
  float o[16];
#pragma unroll
  for (int d = 0; d < 16; ++d) o[d] = acc[d] * inv;
  u16* dst = CTX + ((size_t)(b * S + qrow) * H + h * 64 + j * 16);
  reinterpret_cast<uint4*>(dst)[0] = pack8(o);
  reinterpret_cast<uint4*>(dst)[1] = pack8(o + 8);
}

// ---------- residual + LayerNorm: out = LN(C + Res)*g + b ----------
template<bool CF32, bool RF32, bool OF32>
__global__ __launch_bounds__(256) void ln_res(
    const void* __restrict__ C, const void* __restrict__ Res,
    const float* __restrict__ G, const float* __restrict__ Bb,
    void* __restrict__ Out)
{
  const int H = 1024;
  const int row = blockIdx.x;
  const int tid = threadIdx.x;
  float x[4];
  {
    float c4[4], r4[4];
    if (CF32) {
      const float4 c = reinterpret_cast<const float4*>((const float*)C + (size_t)row * H)[tid];
      c4[0] = c.x; c4[1] = c.y; c4[2] = c.z; c4[3] = c.w;
    } else {
      const uint2 cu = reinterpret_cast<const uint2*>((const u16*)C + (size_t)row * H)[tid];
      c4[0] = __uint_as_float(cu.x << 16); c4[1] = __uint_as_float(cu.x & 0xffff0000u);
      c4[2] = __uint_as_float(cu.y << 16); c4[3] = __uint_as_float(cu.y & 0xffff0000u);
    }
    if (RF32) {
      const float4 rr = reinterpret_cast<const float4*>((const float*)Res + (size_t)row * H)[tid];
      r4[0] = rr.x; r4[1] = rr.y; r4[2] = rr.z; r4[3] = rr.w;
    } else {
      const uint2 ru = reinterpret_cast<const uint2*>((const u16*)Res + (size_t)row * H)[tid];
      r4[0] = __uint_as_float(ru.x << 16); r4[1] = __uint_as_float(ru.x & 0xffff0000u);
      r4[2] = __uint_as_float(ru.y << 16); r4[3] = __uint_as_float(ru.y & 0xffff0000u);
    }
#pragma unroll
    for (int i = 0; i < 4; ++i) x[i] = c4[i] + r4[i];
  }
  float s = x[0] + x[1] + x[2] + x[3];
  float q = x[0] * x[0] + x[1] * x[1] + x[2] * x[2] + x[3] * x[3];
#pragma unroll
  for (int off = 1; off < 64; off <<= 1) {
    s += __shfl_xor(s, off);
    q += __shfl_xor(q, off);
  }
  __shared__ float sb[4][2];
  const int wid = tid >> 6;
  if ((tid & 63) == 0) { sb[wid][0] = s; sb[wid][1] = q; }
  __syncthreads();
  s = sb[0][0] + sb[1][0] + sb[2][0] + sb[3][0];
  q = sb[0][1] + sb[1][1] + sb[2][1] + sb[3][1];
  const float mean = s * (1.f / 1024.f);
  const float var = q * (1.f / 1024.f) - mean * mean;
  const float rstd = rsqrtf(fmaxf(var, 0.f) + 1e-12f);
  const float4 g4 = reinterpret_cast<const float4*>(G)[tid];
  const float4 b4 = reinterpret_cast<const float4*>(Bb)[tid];
  float o[4];
  o[0] = (x[0] - mean) * rstd * g4.x + b4.x;
  o[1] = (x[1] - mean) * rstd * g4.y + b4.y;
  o[2] = (x[2] - mean) * rstd * g4.z + b4.z;
  o[3] = (x[3] - mean) * rstd * g4.w + b4.w;
  if (OF32) {
    reinterpret_cast<float4*>((float*)Out + (size_t)row * H)[tid] =
        make_float4(o[0], o[1], o[2], o[3]);
  } else {
    uint2 pk;
    pk.x = ((u32)f2bf(o[0])) | (((u32)f2bf(o[1])) << 16);
    pk.y = ((u32)f2bf(o[2])) | (((u32)f2bf(o[3])) << 16);
    reinterpret_cast<uint2*>((u16*)Out + (size_t)row * H)[tid] = pk;
  }
}

// ---------- tag gather: tags[t] = bf16(emb_table[ent_ids[t]]) ----------
__global__ void gather_tags(const float* __restrict__ emb, const int* __restrict__ ids,
                            u16* __restrict__ tags)
{
  const int t = blockIdx.x;
  const int id = ids[t];
  const float4* src = reinterpret_cast<const float4*>(emb + (size_t)id * 1024);
  const float4 a = src[threadIdx.x * 2], b = src[threadIdx.x * 2 + 1];
  const float f[8] = {a.x, a.y, a.z, a.w, b.x, b.y, b.z, b.w};
  reinterpret_cast<uint4*>(tags + (size_t)t * 1024)[threadIdx.x] = pack8(f);
}

// ---------- host ----------
extern "C" void kernel_launch(void* const* d_in, const int* in_sizes, int n_in,
                              void* d_out, int out_size, void* d_ws, size_t ws_size,
                              hipStream_t stream)
{
  const int B = 4, S = 2048, H = 1024, FFN = 4096, T = 50;
  const int M = B * S;

  const bool dict_order = (in_sizes[10] == H * H);
  int i_cqw, i_cqb, i_ckw, i_ckb, i_cvw, i_cvb, i_cow, i_cob;
  int i_slng, i_slnb, i_clng, i_clnb, i_olng, i_olnb;
  int i_iw, i_ib, i_ow, i_ob;
  if (dict_order) {
    i_cqw = 10; i_cqb = 11; i_ckw = 12; i_ckb = 13; i_cvw = 14; i_cvb = 15; i_cow = 16; i_cob = 17;
    i_slng = 18; i_slnb = 19; i_clng = 20; i_clnb = 21; i_olng = 22; i_olnb = 23;
    i_iw = 24; i_ib = 25; i_ow = 26; i_ob = 27;
  } else {
    i_slng = 10; i_slnb = 11;
    i_cqw = 12; i_cqb = 13; i_ckw = 14; i_ckb = 15; i_cvw = 16; i_cvb = 17; i_cow = 18; i_cob = 19;
    i_clng = 20; i_clnb = 21;
    i_iw = 22; i_ib = 23; i_ow = 24; i_ob = 25; i_olng = 26; i_olnb = 27;
  }
  const float* X    = (const float*)d_in[0];
  const float* EMB  = (const float*)d_in[1];
  const float* SQW  = (const float*)d_in[2];
  const float* SQB  = (const float*)d_in[3];
  const float* SKW  = (const float*)d_in[4];
  const float* SKB  = (const float*)d_in[5];
  const float* SVW  = (const float*)d_in[6];
  const float* SVB  = (const float*)d_in[7];
  const float* SOW  = (const float*)d_in[8];
  const float* SOB  = (const float*)d_in[9];
  const float* CQW  = (const float*)d_in[i_cqw];
  const float* CQB  = (const float*)d_in[i_cqb];
  const float* CKW  = (const float*)d_in[i_ckw];
  const float* CKB  = (const float*)d_in[i_ckb];
  const float* CVW  = (const float*)d_in[i_cvw];
  const float* CVB  = (const float*)d_in[i_cvb];
  const float* COW  = (const float*)d_in[i_cow];
  const float* COB  = (const float*)d_in[i_cob];
  const float* SLNG = (const float*)d_in[i_slng];
  const float* SLNB = (const float*)d_in[i_slnb];
  const float* CLNG = (const float*)d_in[i_clng];
  const float* CLNB = (const float*)d_in[i_clnb];
  const float* OLNG = (const float*)d_in[i_olng];
  const float* OLNB = (const float*)d_in[i_olnb];
  const float* IW   = (const float*)d_in[i_iw];
  const float* IB   = (const float*)d_in[i_ib];
  const float* OW   = (const float*)d_in[i_ow];
  const float* OB   = (const float*)d_in[i_ob];
  const int* IDS  = (const int*)d_in[28];
  const int* RNG  = (const int*)d_in[29];

  // workspace layout (~115 MB):
  //   0.5MB small bufs | 32MB bf16 transposed weights | 5 x 16MB activation slots
  char* ws = (char*)d_ws;
  u16* tags = (u16*)(ws);
  u16* ktb  = (u16*)(ws + (1 << 17));
  u16* vtb  = (u16*)(ws + (2 << 17));
  char* wreg = ws + (4 << 17);
  const size_t WHH = (size_t)H * H * 2;      // 2 MiB
  u16* wsq = (u16*)(wreg);
  u16* wsk = (u16*)(wreg + WHH);
  u16* wsv = (u16*)(wreg + 2 * WHH);
  u16* wso = (u16*)(wreg + 3 * WHH);
  u16* wcq = (u16*)(wreg + 4 * WHH);
  u16* wck = (u16*)(wreg + 5 * WHH);
  u16* wcv = (u16*)(wreg + 6 * WHH);
  u16* wco = (u16*)(wreg + 7 * WHH);
  u16* wit = (u16*)(wreg + 8 * WHH);                    // [FFN][H]
  u16* wot = (u16*)(wreg + 8 * WHH + (size_t)H * FFN * 2);  // [H][FFN]
  char* slots = wreg + 8 * WHH + 2 * (size_t)H * FFN * 2;
  const size_t SZ = (size_t)M * H * 2;       // 16 MiB
  u16* s0 = (u16*)(slots);
  u16* s1 = (u16*)(slots + SZ);
  u16* s2 = (u16*)(slots + 2 * SZ);
  u16* s3 = (u16*)(slots + 3 * SZ);
  u16* s4 = (u16*)(slots + 4 * SZ);
  u16* inter = s0;                           // M x FFN bf16 spans s0..s3
  float* outp = (float*)d_out;

  const dim3 blk(256);
  const dim3 gsq(H / 128, M / 128);
  const dim3 gt32(H / 32, H / 32);

  // --- prep: convert X, transpose+convert all weights ---
  conv_bf16<<<dim3((M * H / 4 + 255) / 256), blk, 0, stream>>>(X, s4, M * H / 4);
  transpose_conv<<<gt32, blk, 0, stream>>>(SQW, wsq, H, H);
  transpose_conv<<<gt32, blk, 0, stream>>>(SKW, wsk, H, H);
  transpose_conv<<<gt32, blk, 0, stream>>>(SVW, wsv, H, H);
  transpose_conv<<<gt32, blk, 0, stream>>>(SOW, wso, H, H);
  transpose_conv<<<gt32, blk, 0, stream>>>(CQW, wcq, H, H);
  transpose_conv<<<gt32, blk, 0, stream>>>(CKW, wck, H, H);
  transpose_conv<<<gt32, blk, 0, stream>>>(CVW, wcv, H, H);
  transpose_conv<<<gt32, blk, 0, stream>>>(COW, wco, H, H);
  transpose_conv<<<dim3(FFN / 32, H / 32), blk, 0, stream>>>(IW, wit, H, FFN);
  transpose_conv<<<dim3(H / 32, FFN / 32), blk, 0, stream>>>(OW, wot, FFN, H);

  // --- self-attention block ---
  gemm_mfma_k<<<gsq, blk, 0, stream>>>(s4, wsq, SQB, s0, M, H, H, 0);  // q
  gemm_mfma_k<<<gsq, blk, 0, stream>>>(s4, wsk, SKB, s1, M, H, H, 0);  // k
  gemm_mfma_k<<<gsq, blk, 0, stream>>>(s4, wsv, SVB, s2, M, H, H, 0);  // v (s4/Xb dead after)
  attn_self<<<dim3(S / 32, 16, B), blk, 0, stream>>>(s0, s1, s2, s3, RNG);
  gemm_mfma_k<<<gsq, blk, 0, stream>>>(s3, wso, SOB, s0, M, H, H, 0);  // so_out -> s0
  ln_res<false, true, false><<<dim3(M), blk, 0, stream>>>(s0, X, SLNG, SLNB, s3);  // a1 -> s3

  // --- cross-attention block ---
  gather_tags<<<dim3(T), dim3(128), 0, stream>>>(EMB, IDS, tags);
  gemm_mfma_k<<<dim3(H / 128, 1), blk, 0, stream>>>(tags, wck, CKB, ktb, T, H, H, 0);
  gemm_mfma_k<<<dim3(H / 128, 1), blk, 0, stream>>>(tags, wcv, CVB, vtb, T, H, H, 0);
  gemm_mfma_k<<<gsq, blk, 0, stream>>>(s3, wcq, CQB, s0, M, H, H, 0);  // cq
  attn_cross<<<dim3(S / 64, 16, B), blk, 0, stream>>>(s0, ktb, vtb, s1);
  gemm_mfma_k<<<gsq, blk, 0, stream>>>(s1, wco, COB, s2, M, H, H, 0);  // co_out
  ln_res<false, false, false><<<dim3(M), blk, 0, stream>>>(s2, s3, CLNG, CLNB, s4);  // a2 -> s4

  // --- FFN block ---
  gemm_mfma_k<<<dim3(FFN / 128, M / 128), blk, 0, stream>>>(s4, wit, IB, inter, M, FFN, H, 1);
  gemm_mfma_k<<<gsq, blk, 0, stream>>>(inter, wot, OB, outp, M, H, FFN, 2);
  ln_res<true, false, true><<<dim3(M), blk, 0, stream>>>(outp, s4, OLNG, OLNB, outp);
}

// Round 5
// 1495.994 us; speedup vs baseline: 3.5334x; 1.9337x over previous
//
#include <hip/hip_runtime.h>
#include <cstddef>

using u16 = unsigned short;
using u32 = unsigned int;
typedef short bf16x8 __attribute__((ext_vector_type(8)));
typedef float f32x4 __attribute__((ext_vector_type(4)));

// ---------- bf16 helpers ----------
__device__ __forceinline__ u16 f2bf(float f) {
  u32 x = __float_as_uint(f);
  return (u16)((x + 0x7fffu + ((x >> 16) & 1u)) >> 16);  // RNE
}
__device__ __forceinline__ void unpack8(const uint4 u, float* f) {
  f[0] = __uint_as_float(u.x << 16);
  f[1] = __uint_as_float(u.x & 0xffff0000u);
  f[2] = __uint_as_float(u.y << 16);
  f[3] = __uint_as_float(u.y & 0xffff0000u);
  f[4] = __uint_as_float(u.z << 16);
  f[5] = __uint_as_float(u.z & 0xffff0000u);
  f[6] = __uint_as_float(u.w << 16);
  f[7] = __uint_as_float(u.w & 0xffff0000u);
}
__device__ __forceinline__ uint4 pack8(const float* f) {
  uint4 r;
  r.x = ((u32)f2bf(f[0])) | (((u32)f2bf(f[1])) << 16);
  r.y = ((u32)f2bf(f[2])) | (((u32)f2bf(f[3])) << 16);
  r.z = ((u32)f2bf(f[4])) | (((u32)f2bf(f[5])) << 16);
  r.w = ((u32)f2bf(f[6])) | (((u32)f2bf(f[7])) << 16);
  return r;
}

// ---------- MFMA GEMM: C[M,N] = epi(A[M,K] @ Wt[N,K]^T + bias) ----------
__global__ __launch_bounds__(256, 2) void gemm_mfma_k(
    const u16* __restrict__ A, const u16* __restrict__ Wt,
    const float* __restrict__ bias, void* __restrict__ Cout,
    int M, int N, int K, int outmode)
{
  __shared__ u16 As[128][40];
  __shared__ u16 Bs[128][40];
  const int tid = threadIdx.x;
  const int wave = tid >> 6, lane = tid & 63;
  const int wr = wave >> 1, wc = wave & 1;
  const int m0 = blockIdx.y * 128, n0 = blockIdx.x * 128;
  const int lrow = lane & 15, lk = lane >> 4;

  f32x4 acc[4][4];
#pragma unroll
  for (int i = 0; i < 4; ++i)
#pragma unroll
    for (int j = 0; j < 4; ++j) {
      acc[i][j][0] = 0.f; acc[i][j][1] = 0.f; acc[i][j][2] = 0.f; acc[i][j][3] = 0.f;
    }

  const int sr = tid >> 2;
  const int sk = (tid & 3) * 8;
  const bool arow_ok0 = (m0 + sr) < M;
  const bool arow_ok1 = (m0 + sr + 64) < M;

  for (int k0 = 0; k0 < K; k0 += 32) {
    __syncthreads();
    if (arow_ok0)
      *(uint4*)&As[sr][sk] = *(const uint4*)&A[(size_t)(m0 + sr) * K + k0 + sk];
    if (arow_ok1)
      *(uint4*)&As[sr + 64][sk] = *(const uint4*)&A[(size_t)(m0 + sr + 64) * K + k0 + sk];
    *(uint4*)&Bs[sr][sk] = *(const uint4*)&Wt[(size_t)(n0 + sr) * K + k0 + sk];
    *(uint4*)&Bs[sr + 64][sk] = *(const uint4*)&Wt[(size_t)(n0 + sr + 64) * K + k0 + sk];
    __syncthreads();

    bf16x8 af[4], bf[4];
#pragma unroll
    for (int i = 0; i < 4; ++i) {
      af[i] = *(const bf16x8*)&As[wr * 64 + i * 16 + lrow][lk * 8];
      bf[i] = *(const bf16x8*)&Bs[wc * 64 + i * 16 + lrow][lk * 8];
    }
#pragma unroll
    for (int i = 0; i < 4; ++i)
#pragma unroll
      for (int j = 0; j < 4; ++j)
        acc[i][j] = __builtin_amdgcn_mfma_f32_16x16x32_bf16(af[i], bf[j], acc[i][j], 0, 0, 0);
  }

#pragma unroll
  for (int j = 0; j < 4; ++j) {
    const int gcol = n0 + wc * 64 + j * 16 + lrow;
    const float bj = bias[gcol];
#pragma unroll
    for (int i = 0; i < 4; ++i) {
      const int rbase = m0 + wr * 64 + i * 16 + lk * 4;
#pragma unroll
      for (int reg = 0; reg < 4; ++reg) {
        const int grow = rbase + reg;
        if (grow >= M) continue;
        float c = acc[i][j][reg] + bj;
        if (outmode == 1) c = 0.5f * c * (1.0f + erff(c * 0.70710678118654752f));
        if (outmode == 2)
          ((float*)Cout)[(size_t)grow * N + gcol] = c;
        else
          ((u16*)Cout)[(size_t)grow * N + gcol] = f2bf(c);
      }
    }
  }
}

// ---------- weight transpose+convert ----------
__global__ __launch_bounds__(256) void transpose_conv(
    const float* __restrict__ W, u16* __restrict__ Wt, int K, int N)
{
  __shared__ float t[32][33];
  const int kb = blockIdx.y * 32, nb = blockIdx.x * 32;
  const int x = threadIdx.x & 31;
  const int y4 = (threadIdx.x >> 5) * 4;
#pragma unroll
  for (int i = 0; i < 4; ++i)
    t[y4 + i][x] = W[(size_t)(kb + y4 + i) * N + nb + x];
  __syncthreads();
#pragma unroll
  for (int i = 0; i < 4; ++i)
    Wt[(size_t)(nb + y4 + i) * K + kb + x] = f2bf(t[x][y4 + i]);
}

// ---------- elementwise fp32 -> bf16 ----------
__global__ __launch_bounds__(256) void conv_bf16(
    const float* __restrict__ in, u16* __restrict__ out, int n4)
{
  const int idx = blockIdx.x * 256 + threadIdx.x;
  if (idx >= n4) return;
  const float4 v = reinterpret_cast<const float4*>(in)[idx];
  const float f[4] = {v.x, v.y, v.z, v.w};
  uint2 pk;
  pk.x = ((u32)f2bf(f[0])) | (((u32)f2bf(f[1])) << 16);
  pk.y = ((u32)f2bf(f[2])) | (((u32)f2bf(f[3])) << 16);
  reinterpret_cast<uint2*>(out)[idx] = pk;
}

// ---------- MFMA flash self-attention (band mask ADDS +1.0 in-band) ----------
// grid (S/128, NH, B), 256 thr (4 waves). Wave owns 32 q-rows. KV chunks of 64.
// Q in registers (A-frags), K from global (B-frags), V transposed in LDS,
// P via per-wave LDS tile. Online softmax in D-fragment layout.
__global__ __launch_bounds__(256, 3) void attn_self_mfma(
    const u16* __restrict__ Q, const u16* __restrict__ K,
    const u16* __restrict__ V, u16* __restrict__ CTX,
    const int* __restrict__ rngp)
{
  const int S = 2048, H = 1024;
  const int qt = blockIdx.x, h = blockIdx.y, b = blockIdx.z;
  const int range = rngp[0];
  const int tid = threadIdx.x;
  const int wave = tid >> 6, lane = tid & 63;
  const int lcol = lane & 15;   // fragment col
  const int lgrp = lane >> 4;   // 0..3

  __shared__ u16 Vt[64][72];       // [d][k] transposed V chunk
  __shared__ u16 Pb[4][32][72];    // per-wave P tile [q][k]

  const int qbase = qt * 128 + wave * 32;

  // Q fragments (A-operand): row = lane&15, d-slice = lgrp*8, per (rowfrag, d-half)
  bf16x8 qf[2][2];
#pragma unroll
  for (int rf = 0; rf < 2; ++rf)
#pragma unroll
    for (int dh = 0; dh < 2; ++dh) {
      const int qrow = qbase + rf * 16 + lcol;
      qf[rf][dh] = *(const bf16x8*)&Q[((size_t)(b * S + qrow)) * H + h * 64 + dh * 32 + lgrp * 8];
    }

  f32x4 acc[2][4];
#pragma unroll
  for (int rf = 0; rf < 2; ++rf)
#pragma unroll
    for (int df = 0; df < 4; ++df) {
      acc[rf][df][0] = 0.f; acc[rf][df][1] = 0.f; acc[rf][df][2] = 0.f; acc[rf][df][3] = 0.f;
    }
  float mreg[2][4], lreg[2][4];
#pragma unroll
  for (int rf = 0; rf < 2; ++rf)
#pragma unroll
    for (int reg = 0; reg < 4; ++reg) { mreg[rf][reg] = -1e30f; lreg[rf][reg] = 0.f; }

  for (int c = 0; c < 32; ++c) {
    const int kb = c * 64;
    __syncthreads();  // prev Vt fully consumed
    // --- stage Vt (conflict-free: lane = k-row, wave = d-segment of 16) ---
    {
      const u16* vsrc = &V[((size_t)(b * S + kb + lane)) * H + h * 64 + wave * 16];
      uint4 u0 = *(const uint4*)vsrc;
      uint4 u1 = *(const uint4*)(vsrc + 8);
      u16 tmp[16];
      *(uint4*)tmp = u0; *(uint4*)(tmp + 8) = u1;
#pragma unroll
      for (int i = 0; i < 16; ++i) Vt[wave * 16 + i][lane] = tmp[i];
    }
    // --- QK^T: S[32q][64k] per wave ---
    f32x4 s[2][4];
#pragma unroll
    for (int rf = 0; rf < 2; ++rf)
#pragma unroll
      for (int cf = 0; cf < 4; ++cf) {
        s[rf][cf][0] = 0.f; s[rf][cf][1] = 0.f; s[rf][cf][2] = 0.f; s[rf][cf][3] = 0.f;
      }
#pragma unroll
    for (int dh = 0; dh < 2; ++dh)
#pragma unroll
      for (int cf = 0; cf < 4; ++cf) {
        const int krow = kb + cf * 16 + lcol;
        const bf16x8 kf = *(const bf16x8*)&K[((size_t)(b * S + krow)) * H + h * 64 + dh * 32 + lgrp * 8];
#pragma unroll
        for (int rf = 0; rf < 2; ++rf)
          s[rf][cf] = __builtin_amdgcn_mfma_f32_16x16x32_bf16(qf[rf][dh], kf, s[rf][cf], 0, 0, 0);
      }
    // --- mask + online softmax (rows live at (lgrp*4+reg), cols at lcol+16*cf) ---
#pragma unroll
    for (int rf = 0; rf < 2; ++rf) {
#pragma unroll
      for (int reg = 0; reg < 4; ++reg) {
        const int qrow = qbase + rf * 16 + lgrp * 4 + reg;
        float rmax = -1e30f;
#pragma unroll
        for (int cf = 0; cf < 4; ++cf) {
          const int kcol = kb + cf * 16 + lcol;
          int dd = qrow - kcol; if (dd < 0) dd = -dd;
          const float v = s[rf][cf][reg] * 0.125f + ((dd <= range) ? 1.0f : 0.0f);
          s[rf][cf][reg] = v;
          rmax = fmaxf(rmax, v);
        }
        rmax = fmaxf(rmax, __shfl_xor(rmax, 1));
        rmax = fmaxf(rmax, __shfl_xor(rmax, 2));
        rmax = fmaxf(rmax, __shfl_xor(rmax, 4));
        rmax = fmaxf(rmax, __shfl_xor(rmax, 8));
        const float newm = fmaxf(mreg[rf][reg], rmax);
        const float corr = expf(mreg[rf][reg] - newm);
        float rsum = 0.f;
#pragma unroll
        for (int cf = 0; cf < 4; ++cf) {
          const float e = expf(s[rf][cf][reg] - newm);
          s[rf][cf][reg] = e;
          rsum += e;
        }
        rsum += __shfl_xor(rsum, 1);
        rsum += __shfl_xor(rsum, 2);
        rsum += __shfl_xor(rsum, 4);
        rsum += __shfl_xor(rsum, 8);
        lreg[rf][reg] = lreg[rf][reg] * corr + rsum;
        mreg[rf][reg] = newm;
#pragma unroll
        for (int df = 0; df < 4; ++df) acc[rf][df][reg] *= corr;
      }
    }
    // --- write P (wave-local LDS, no barrier needed) ---
#pragma unroll
    for (int rf = 0; rf < 2; ++rf)
#pragma unroll
      for (int reg = 0; reg < 4; ++reg)
#pragma unroll
        for (int cf = 0; cf < 4; ++cf)
          Pb[wave][rf * 16 + lgrp * 4 + reg][cf * 16 + lcol] = f2bf(s[rf][cf][reg]);
    __syncthreads();  // Vt staged
    // --- PV: acc[32q][64d] += P[32q][64k] x V[64k][64d] ---
#pragma unroll
    for (int ks = 0; ks < 2; ++ks) {
      bf16x8 pa[2], vb[4];
#pragma unroll
      for (int rf = 0; rf < 2; ++rf)
        pa[rf] = *(const bf16x8*)&Pb[wave][rf * 16 + lcol][ks * 32 + lgrp * 8];
#pragma unroll
      for (int df = 0; df < 4; ++df)
        vb[df] = *(const bf16x8*)&Vt[df * 16 + lcol][ks * 32 + lgrp * 8];
#pragma unroll
      for (int rf = 0; rf < 2; ++rf)
#pragma unroll
        for (int df = 0; df < 4; ++df)
          acc[rf][df] = __builtin_amdgcn_mfma_f32_16x16x32_bf16(pa[rf], vb[df], acc[rf][df], 0, 0, 0);
    }
  }
  // --- epilogue ---
#pragma unroll
  for (int rf = 0; rf < 2; ++rf)
#pragma unroll
    for (int reg = 0; reg < 4; ++reg) {
      const int qrow = qbase + rf * 16 + lgrp * 4 + reg;
      const float inv = 1.f / lreg[rf][reg];
#pragma unroll
      for (int df = 0; df < 4; ++df)
        CTX[((size_t)(b * S + qrow)) * H + h * 64 + df * 16 + lcol] =
            f2bf(acc[rf][df][reg] * inv);
    }
}

// ---------- cross-attention (T=50 keys, no mask), bf16 I/O ----------
__global__ __launch_bounds__(256, 1) void attn_cross(
    const u16* __restrict__ Q, const u16* __restrict__ KT,
    const u16* __restrict__ VT, u16* __restrict__ CTX)
{
  const int S = 2048, H = 1024, T = 50;
  const int qt = blockIdx.x, h = blockIdx.y, b = blockIdx.z;
  const int tid = threadIdx.x;
  const int r = tid >> 2, j = tid & 3;
  __shared__ float kt[50][68], vt[50][68];
  __shared__ float qs[64][68];
  __shared__ float ps[64][52];

  for (int idx = tid; idx < T * 8; idx += 256) {
    const int row = idx >> 3, seg = idx & 7;
    float f[8];
    unpack8(reinterpret_cast<const uint4*>(KT + (size_t)row * H + h * 64 + seg * 8)[0], f);
#pragma unroll
    for (int d = 0; d < 8; ++d) kt[row][seg * 8 + d] = f[d];
    unpack8(reinterpret_cast<const uint4*>(VT + (size_t)row * H + h * 64 + seg * 8)[0], f);
#pragma unroll
    for (int d = 0; d < 8; ++d) vt[row][seg * 8 + d] = f[d];
  }
  const int qrow = qt * 64 + r;
  {
    const uint4* qp = reinterpret_cast<const uint4*>(Q + ((size_t)(b * S + qrow) * H + h * 64 + j * 16));
    float f[16];
    unpack8(qp[0], f); unpack8(qp[1], f + 8);
#pragma unroll
    for (int d = 0; d < 16; ++d) qs[r][j * 16 + d] = f[d];
  }
  __syncthreads();

  float sreg[13];
  float rmax = -1e30f;
#pragma unroll
  for (int i = 0; i < 13; ++i) {
    const int k = j + 4 * i;
    float s = -1e30f;
    if (k < T) {
      float acc = 0.f;
      const float4* qr4 = reinterpret_cast<const float4*>(&qs[r][0]);
      const float4* kr4 = reinterpret_cast<const float4*>(&kt[k][0]);
#pragma unroll
      for (int d4 = 0; d4 < 16; ++d4) {
        const float4 qv = qr4[d4], kv = kr4[d4];
        acc += qv.x * kv.x + qv.y * kv.y + qv.z * kv.z + qv.w * kv.w;
      }
      s = acc * 0.125f;
    }
    sreg[i] = s;
    rmax = fmaxf(rmax, s);
  }
  rmax = fmaxf(rmax, __shfl_xor(rmax, 1));
  rmax = fmaxf(rmax, __shfl_xor(rmax, 2));
  float rsum = 0.f;
#pragma unroll
  for (int i = 0; i < 13; ++i) {
    const int k = j + 4 * i;
    if (k < T) {
      const float e = expf(sreg[i] - rmax);
      ps[r][k] = e;
      rsum += e;
    }
  }
  rsum += __shfl_xor(rsum, 1);
  rsum += __shfl_xor(rsum, 2);
  const float inv = 1.f / rsum;

  float acc[16];
#pragma unroll
  for (int d = 0; d < 16; ++d) acc[d] = 0.f;
  for (int k = 0; k < T; ++k) {
    const float p = ps[r][k];
    const float4* vr4 = reinterpret_cast<const float4*>(&vt[k][0]);
#pragma unroll
    for (int q4 = 0; q4 < 4; ++q4) {
      const float4 v = vr4[j * 4 + q4];
      acc[q4 * 4 + 0] = fmaf(p, v.x, acc[q4 * 4 + 0]);
      acc[q4 * 4 + 1] = fmaf(p, v.y, acc[q4 * 4 + 1]);
      acc[q4 * 4 + 2] = fmaf(p, v.z, acc[q4 * 4 + 2]);
      acc[q4 * 4 + 3] = fmaf(p, v.w, acc[q4 * 4 + 3]);
    }
  }
  float o[16];
#pragma unroll
  for (int d = 0; d < 16; ++d) o[d] = acc[d] * inv;
  u16* dst = CTX + ((size_t)(b * S + qrow) * H + h * 64 + j * 16);
  reinterpret_cast<uint4*>(dst)[0] = pack8(o);
  reinterpret_cast<uint4*>(dst)[1] = pack8(o + 8);
}

// ---------- residual + LayerNorm ----------
template<bool CF32, bool RF32, bool OF32>
__global__ __launch_bounds__(256) void ln_res(
    const void* __restrict__ C, const void* __restrict__ Res,
    const float* __restrict__ G, const float* __restrict__ Bb,
    void* __restrict__ Out)
{
  const int H = 1024;
  const int row = blockIdx.x;
  const int tid = threadIdx.x;
  float x[4];
  {
    float c4[4], r4[4];
    if (CF32) {
      const float4 c = reinterpret_cast<const float4*>((const float*)C + (size_t)row * H)[tid];
      c4[0] = c.x; c4[1] = c.y; c4[2] = c.z; c4[3] = c.w;
    } else {
      const uint2 cu = reinterpret_cast<const uint2*>((const u16*)C + (size_t)row * H)[tid];
      c4[0] = __uint_as_float(cu.x << 16); c4[1] = __uint_as_float(cu.x & 0xffff0000u);
      c4[2] = __uint_as_float(cu.y << 16); c4[3] = __uint_as_float(cu.y & 0xffff0000u);
    }
    if (RF32) {
      const float4 rr = reinterpret_cast<const float4*>((const float*)Res + (size_t)row * H)[tid];
      r4[0] = rr.x; r4[1] = rr.y; r4[2] = rr.z; r4[3] = rr.w;
    } else {
      const uint2 ru = reinterpret_cast<const uint2*>((const u16*)Res + (size_t)row * H)[tid];
      r4[0] = __uint_as_float(ru.x << 16); r4[1] = __uint_as_float(ru.x & 0xffff0000u);
      r4[2] = __uint_as_float(ru.y << 16); r4[3] = __uint_as_float(ru.y & 0xffff0000u);
    }
#pragma unroll
    for (int i = 0; i < 4; ++i) x[i] = c4[i] + r4[i];
  }
  float s = x[0] + x[1] + x[2] + x[3];
  float q = x[0] * x[0] + x[1] * x[1] + x[2] * x[2] + x[3] * x[3];
#pragma unroll
  for (int off = 1; off < 64; off <<= 1) {
    s += __shfl_xor(s, off);
    q += __shfl_xor(q, off);
  }
  __shared__ float sb[4][2];
  const int wid = tid >> 6;
  if ((tid & 63) == 0) { sb[wid][0] = s; sb[wid][1] = q; }
  __syncthreads();
  s = sb[0][0] + sb[1][0] + sb[2][0] + sb[3][0];
  q = sb[0][1] + sb[1][1] + sb[2][1] + sb[3][1];
  const float mean = s * (1.f / 1024.f);
  const float var = q * (1.f / 1024.f) - mean * mean;
  const float rstd = rsqrtf(fmaxf(var, 0.f) + 1e-12f);
  const float4 g4 = reinterpret_cast<const float4*>(G)[tid];
  const float4 b4 = reinterpret_cast<const float4*>(Bb)[tid];
  float o[4];
  o[0] = (x[0] - mean) * rstd * g4.x + b4.x;
  o[1] = (x[1] - mean) * rstd * g4.y + b4.y;
  o[2] = (x[2] - mean) * rstd * g4.z + b4.z;
  o[3] = (x[3] - mean) * rstd * g4.w + b4.w;
  if (OF32) {
    reinterpret_cast<float4*>((float*)Out + (size_t)row * H)[tid] =
        make_float4(o[0], o[1], o[2], o[3]);
  } else {
    uint2 pk;
    pk.x = ((u32)f2bf(o[0])) | (((u32)f2bf(o[1])) << 16);
    pk.y = ((u32)f2bf(o[2])) | (((u32)f2bf(o[3])) << 16);
    reinterpret_cast<uint2*>((u16*)Out + (size_t)row * H)[tid] = pk;
  }
}

// ---------- tag gather ----------
__global__ void gather_tags(const float* __restrict__ emb, const int* __restrict__ ids,
                            u16* __restrict__ tags)
{
  const int t = blockIdx.x;
  const int id = ids[t];
  const float4* src = reinterpret_cast<const float4*>(emb + (size_t)id * 1024);
  const float4 a = src[threadIdx.x * 2], b = src[threadIdx.x * 2 + 1];
  const float f[8] = {a.x, a.y, a.z, a.w, b.x, b.y, b.z, b.w};
  reinterpret_cast<uint4*>(tags + (size_t)t * 1024)[threadIdx.x] = pack8(f);
}

// ---------- host ----------
extern "C" void kernel_launch(void* const* d_in, const int* in_sizes, int n_in,
                              void* d_out, int out_size, void* d_ws, size_t ws_size,
                              hipStream_t stream)
{
  const int B = 4, S = 2048, H = 1024, FFN = 4096, T = 50;
  const int M = B * S;

  const bool dict_order = (in_sizes[10] == H * H);
  int i_cqw, i_cqb, i_ckw, i_ckb, i_cvw, i_cvb, i_cow, i_cob;
  int i_slng, i_slnb, i_clng, i_clnb, i_olng, i_olnb;
  int i_iw, i_ib, i_ow, i_ob;
  if (dict_order) {
    i_cqw = 10; i_cqb = 11; i_ckw = 12; i_ckb = 13; i_cvw = 14; i_cvb = 15; i_cow = 16; i_cob = 17;
    i_slng = 18; i_slnb = 19; i_clng = 20; i_clnb = 21; i_olng = 22; i_olnb = 23;
    i_iw = 24; i_ib = 25; i_ow = 26; i_ob = 27;
  } else {
    i_slng = 10; i_slnb = 11;
    i_cqw = 12; i_cqb = 13; i_ckw = 14; i_ckb = 15; i_cvw = 16; i_cvb = 17; i_cow = 18; i_cob = 19;
    i_clng = 20; i_clnb = 21;
    i_iw = 22; i_ib = 23; i_ow = 24; i_ob = 25; i_olng = 26; i_olnb = 27;
  }
  const float* X    = (const float*)d_in[0];
  const float* EMB  = (const float*)d_in[1];
  const float* SQW  = (const float*)d_in[2];
  const float* SQB  = (const float*)d_in[3];
  const float* SKW  = (const float*)d_in[4];
  const float* SKB  = (const float*)d_in[5];
  const float* SVW  = (const float*)d_in[6];
  const float* SVB  = (const float*)d_in[7];
  const float* SOW  = (const float*)d_in[8];
  const float* SOB  = (const float*)d_in[9];
  const float* CQW  = (const float*)d_in[i_cqw];
  const float* CQB  = (const float*)d_in[i_cqb];
  const float* CKW  = (const float*)d_in[i_ckw];
  const float* CKB  = (const float*)d_in[i_ckb];
  const float* CVW  = (const float*)d_in[i_cvw];
  const float* CVB  = (const float*)d_in[i_cvb];
  const float* COW  = (const float*)d_in[i_cow];
  const float* COB  = (const float*)d_in[i_cob];
  const float* SLNG = (const float*)d_in[i_slng];
  const float* SLNB = (const float*)d_in[i_slnb];
  const float* CLNG = (const float*)d_in[i_clng];
  const float* CLNB = (const float*)d_in[i_clnb];
  const float* OLNG = (const float*)d_in[i_olng];
  const float* OLNB = (const float*)d_in[i_olnb];
  const float* IW   = (const float*)d_in[i_iw];
  const float* IB   = (const float*)d_in[i_ib];
  const float* OW   = (const float*)d_in[i_ow];
  const float* OB   = (const float*)d_in[i_ob];
  const int* IDS  = (const int*)d_in[28];
  const int* RNG  = (const int*)d_in[29];

  char* ws = (char*)d_ws;
  u16* tags = (u16*)(ws);
  u16* ktb  = (u16*)(ws + (1 << 17));
  u16* vtb  = (u16*)(ws + (2 << 17));
  char* wreg = ws + (4 << 17);
  const size_t WHH = (size_t)H * H * 2;
  u16* wsq = (u16*)(wreg);
  u16* wsk = (u16*)(wreg + WHH);
  u16* wsv = (u16*)(wreg + 2 * WHH);
  u16* wso = (u16*)(wreg + 3 * WHH);
  u16* wcq = (u16*)(wreg + 4 * WHH);
  u16* wck = (u16*)(wreg + 5 * WHH);
  u16* wcv = (u16*)(wreg + 6 * WHH);
  u16* wco = (u16*)(wreg + 7 * WHH);
  u16* wit = (u16*)(wreg + 8 * WHH);
  u16* wot = (u16*)(wreg + 8 * WHH + (size_t)H * FFN * 2);
  char* slots = wreg + 8 * WHH + 2 * (size_t)H * FFN * 2;
  const size_t SZ = (size_t)M * H * 2;
  u16* s0 = (u16*)(slots);
  u16* s1 = (u16*)(slots + SZ);
  u16* s2 = (u16*)(slots + 2 * SZ);
  u16* s3 = (u16*)(slots + 3 * SZ);
  u16* s4 = (u16*)(slots + 4 * SZ);
  u16* inter = s0;
  float* outp = (float*)d_out;

  const dim3 blk(256);
  const dim3 gsq(H / 128, M / 128);
  const dim3 gt32(H / 32, H / 32);

  conv_bf16<<<dim3((M * H / 4 + 255) / 256), blk, 0, stream>>>(X, s4, M * H / 4);
  transpose_conv<<<gt32, blk, 0, stream>>>(SQW, wsq, H, H);
  transpose_conv<<<gt32, blk, 0, stream>>>(SKW, wsk, H, H);
  transpose_conv<<<gt32, blk, 0, stream>>>(SVW, wsv, H, H);
  transpose_conv<<<gt32, blk, 0, stream>>>(SOW, wso, H, H);
  transpose_conv<<<gt32, blk, 0, stream>>>(CQW, wcq, H, H);
  transpose_conv<<<gt32, blk, 0, stream>>>(CKW, wck, H, H);
  transpose_conv<<<gt32, blk, 0, stream>>>(CVW, wcv, H, H);
  transpose_conv<<<gt32, blk, 0, stream>>>(COW, wco, H, H);
  transpose_conv<<<dim3(FFN / 32, H / 32), blk, 0, stream>>>(IW, wit, H, FFN);
  transpose_conv<<<dim3(H / 32, FFN / 32), blk, 0, stream>>>(OW, wot, FFN, H);

  // --- self-attention block ---
  gemm_mfma_k<<<gsq, blk, 0, stream>>>(s4, wsq, SQB, s0, M, H, H, 0);  // q
  gemm_mfma_k<<<gsq, blk, 0, stream>>>(s4, wsk, SKB, s1, M, H, H, 0);  // k
  gemm_mfma_k<<<gsq, blk, 0, stream>>>(s4, wsv, SVB, s2, M, H, H, 0);  // v
  attn_self_mfma<<<dim3(S / 128, 16, B), blk, 0, stream>>>(s0, s1, s2, s3, RNG);
  gemm_mfma_k<<<gsq, blk, 0, stream>>>(s3, wso, SOB, s0, M, H, H, 0);  // so_out
  ln_res<false, true, false><<<dim3(M), blk, 0, stream>>>(s0, X, SLNG, SLNB, s3);

  // --- cross-attention block ---
  gather_tags<<<dim3(T), dim3(128), 0, stream>>>(EMB, IDS, tags);
  gemm_mfma_k<<<dim3(H / 128, 1), blk, 0, stream>>>(tags, wck, CKB, ktb, T, H, H, 0);
  gemm_mfma_k<<<dim3(H / 128, 1), blk, 0, stream>>>(tags, wcv, CVB, vtb, T, H, H, 0);
  gemm_mfma_k<<<gsq, blk, 0, stream>>>(s3, wcq, CQB, s0, M, H, H, 0);  // cq
  attn_cross<<<dim3(S / 64, 16, B), blk, 0, stream>>>(s0, ktb, vtb, s1);
  gemm_mfma_k<<<gsq, blk, 0, stream>>>(s1, wco, COB, s2, M, H, H, 0);  // co_out
  ln_res<false, false, false><<<dim3(M), blk, 0, stream>>>(s2, s3, CLNG, CLNB, s4);

  // --- FFN block ---
  gemm_mfma_k<<<dim3(FFN / 128, M / 128), blk, 0, stream>>>(s4, wit, IB, inter, M, FFN, H, 1);
  gemm_mfma_k<<<gsq, blk, 0, stream>>>(inter, wot, OB, outp, M, H, FFN, 2);
  ln_res<true, false, true><<<dim3(M), blk, 0, stream>>>(outp, s4, OLNG, OLNB, outp);
}

// Round 6
// 1248.672 us; speedup vs baseline: 4.2333x; 1.1981x over previous
//
#include <hip/hip_runtime.h>
#include <cstddef>

using u16 = unsigned short;
using u32 = unsigned int;
typedef short bf16x8 __attribute__((ext_vector_type(8)));
typedef float f32x4 __attribute__((ext_vector_type(4)));

// ---------- bf16 helpers ----------
__device__ __forceinline__ u16 f2bf(float f) {
  u32 x = __float_as_uint(f);
  return (u16)((x + 0x7fffu + ((x >> 16) & 1u)) >> 16);  // RNE
}
__device__ __forceinline__ void unpack8(const uint4 u, float* f) {
  f[0] = __uint_as_float(u.x << 16);
  f[1] = __uint_as_float(u.x & 0xffff0000u);
  f[2] = __uint_as_float(u.y << 16);
  f[3] = __uint_as_float(u.y & 0xffff0000u);
  f[4] = __uint_as_float(u.z << 16);
  f[5] = __uint_as_float(u.z & 0xffff0000u);
  f[6] = __uint_as_float(u.w << 16);
  f[7] = __uint_as_float(u.w & 0xffff0000u);
}
__device__ __forceinline__ uint4 pack8(const float* f) {
  uint4 r;
  r.x = ((u32)f2bf(f[0])) | (((u32)f2bf(f[1])) << 16);
  r.y = ((u32)f2bf(f[2])) | (((u32)f2bf(f[3])) << 16);
  r.z = ((u32)f2bf(f[4])) | (((u32)f2bf(f[5])) << 16);
  r.w = ((u32)f2bf(f[6])) | (((u32)f2bf(f[7])) << 16);
  return r;
}
__device__ __forceinline__ float fast_exp2(float x) {
  float r; asm("v_exp_f32 %0, %1" : "=v"(r) : "v"(x)); return r;
}
__device__ __forceinline__ float gelu_f(float x) {
  // tanh-form GELU via v_exp_f32 (|err| vs exact erf-GELU < ~1e-3)
  const float u = x * (0.7978845608f + 0.0356774081f * x * x);
  const float e = fast_exp2(u * 2.8853900818f);  // exp(2u)
  const float t = 1.f - 2.f / (e + 1.f);
  return 0.5f * x * (1.f + t);
}
__device__ __forceinline__ void gload16(const void* g, void* l) {
  __builtin_amdgcn_global_load_lds(
      (const __attribute__((address_space(1))) u32*)g,
      (__attribute__((address_space(3))) u32*)l, 16, 0, 0);
}

// ---------- MFMA GEMM (M%128==0): C = epi(A[M,K] @ Wt[N,K]^T + bias) ----------
// global_load_lds staging into linear LDS [128][32] u16 with XOR swizzle
// (source-side + read-side involution: colbyte ^= ((row>>1)&3)<<4).
__global__ __launch_bounds__(256, 2) void gemm_mfma_g(
    const u16* __restrict__ A, const u16* __restrict__ Wt,
    const float* __restrict__ bias, void* __restrict__ Cout,
    int M, int N, int K, int outmode)
{
  __shared__ u16 As[128 * 32];
  __shared__ u16 Bs[128 * 32];
  const int tid = threadIdx.x;
  const int wave = tid >> 6, lane = tid & 63;
  const int wr = wave >> 1, wc = wave & 1;
  const int m0 = blockIdx.y * 128, n0 = blockIdx.x * 128;
  const int lrow = lane & 15, lk = lane >> 4;

  // staging: wave covers rows [wave*32, wave*32+32), two 16-row loads each for A,B
  const int rr = lane >> 2;            // 0..15 relative row within a load
  const int cbl = (lane & 3) * 16;     // byte col within 64B row

  f32x4 acc[4][4];
#pragma unroll
  for (int i = 0; i < 4; ++i)
#pragma unroll
    for (int j = 0; j < 4; ++j) {
      acc[i][j][0] = 0.f; acc[i][j][1] = 0.f; acc[i][j][2] = 0.f; acc[i][j][3] = 0.f;
    }

  for (int k0 = 0; k0 < K; k0 += 32) {
    __syncthreads();
#pragma unroll
    for (int i = 0; i < 2; ++i) {
      const int Rloc = wave * 32 + i * 16 + rr;             // tile-local row
      const int scb = cbl ^ (((Rloc >> 1) & 3) << 4);       // swizzled source col-byte
      gload16(A + (size_t)(m0 + Rloc) * K + k0 + (scb >> 1),
              &As[(wave * 32 + i * 16) * 32]);
      gload16(Wt + (size_t)(n0 + Rloc) * K + k0 + (scb >> 1),
              &Bs[(wave * 32 + i * 16) * 32]);
    }
    __syncthreads();  // compiler drains vmcnt(0) before s_barrier

    bf16x8 af[4], bf[4];
#pragma unroll
    for (int i = 0; i < 4; ++i) {
      const int rA = wr * 64 + i * 16 + lrow;
      af[i] = *(const bf16x8*)&As[rA * 32 + ((lk * 16 ^ (((rA >> 1) & 3) << 4)) >> 1)];
      const int rB = wc * 64 + i * 16 + lrow;
      bf[i] = *(const bf16x8*)&Bs[rB * 32 + ((lk * 16 ^ (((rB >> 1) & 3) << 4)) >> 1)];
    }
#pragma unroll
    for (int i = 0; i < 4; ++i)
#pragma unroll
      for (int j = 0; j < 4; ++j)
        acc[i][j] = __builtin_amdgcn_mfma_f32_16x16x32_bf16(af[i], bf[j], acc[i][j], 0, 0, 0);
  }

#pragma unroll
  for (int j = 0; j < 4; ++j) {
    const int gcol = n0 + wc * 64 + j * 16 + lrow;
    const float bj = bias[gcol];
#pragma unroll
    for (int i = 0; i < 4; ++i) {
      const int rbase = m0 + wr * 64 + i * 16 + lk * 4;
#pragma unroll
      for (int reg = 0; reg < 4; ++reg) {
        float c = acc[i][j][reg] + bj;
        if (outmode == 1) c = gelu_f(c);
        if (outmode == 2)
          ((float*)Cout)[(size_t)(rbase + reg) * N + gcol] = c;
        else
          ((u16*)Cout)[(size_t)(rbase + reg) * N + gcol] = f2bf(c);
      }
    }
  }
}

// ---------- MFMA GEMM, guarded (small M, e.g. tags M=50) ----------
__global__ __launch_bounds__(256, 2) void gemm_mfma_k(
    const u16* __restrict__ A, const u16* __restrict__ Wt,
    const float* __restrict__ bias, void* __restrict__ Cout,
    int M, int N, int K, int outmode)
{
  __shared__ u16 As[128][40];
  __shared__ u16 Bs[128][40];
  const int tid = threadIdx.x;
  const int wave = tid >> 6, lane = tid & 63;
  const int wr = wave >> 1, wc = wave & 1;
  const int m0 = blockIdx.y * 128, n0 = blockIdx.x * 128;
  const int lrow = lane & 15, lk = lane >> 4;

  f32x4 acc[4][4];
#pragma unroll
  for (int i = 0; i < 4; ++i)
#pragma unroll
    for (int j = 0; j < 4; ++j) {
      acc[i][j][0] = 0.f; acc[i][j][1] = 0.f; acc[i][j][2] = 0.f; acc[i][j][3] = 0.f;
    }

  const int sr = tid >> 2;
  const int sk = (tid & 3) * 8;
  const bool arow_ok0 = (m0 + sr) < M;
  const bool arow_ok1 = (m0 + sr + 64) < M;

  for (int k0 = 0; k0 < K; k0 += 32) {
    __syncthreads();
    if (arow_ok0)
      *(uint4*)&As[sr][sk] = *(const uint4*)&A[(size_t)(m0 + sr) * K + k0 + sk];
    if (arow_ok1)
      *(uint4*)&As[sr + 64][sk] = *(const uint4*)&A[(size_t)(m0 + sr + 64) * K + k0 + sk];
    *(uint4*)&Bs[sr][sk] = *(const uint4*)&Wt[(size_t)(n0 + sr) * K + k0 + sk];
    *(uint4*)&Bs[sr + 64][sk] = *(const uint4*)&Wt[(size_t)(n0 + sr + 64) * K + k0 + sk];
    __syncthreads();

    bf16x8 af[4], bf[4];
#pragma unroll
    for (int i = 0; i < 4; ++i) {
      af[i] = *(const bf16x8*)&As[wr * 64 + i * 16 + lrow][lk * 8];
      bf[i] = *(const bf16x8*)&Bs[wc * 64 + i * 16 + lrow][lk * 8];
    }
#pragma unroll
    for (int i = 0; i < 4; ++i)
#pragma unroll
      for (int j = 0; j < 4; ++j)
        acc[i][j] = __builtin_amdgcn_mfma_f32_16x16x32_bf16(af[i], bf[j], acc[i][j], 0, 0, 0);
  }

#pragma unroll
  for (int j = 0; j < 4; ++j) {
    const int gcol = n0 + wc * 64 + j * 16 + lrow;
    const float bj = bias[gcol];
#pragma unroll
    for (int i = 0; i < 4; ++i) {
      const int rbase = m0 + wr * 64 + i * 16 + lk * 4;
#pragma unroll
      for (int reg = 0; reg < 4; ++reg) {
        const int grow = rbase + reg;
        if (grow >= M) continue;
        float c = acc[i][j][reg] + bj;
        if (outmode == 1) c = gelu_f(c);
        if (outmode == 2)
          ((float*)Cout)[(size_t)grow * N + gcol] = c;
        else
          ((u16*)Cout)[(size_t)grow * N + gcol] = f2bf(c);
      }
    }
  }
}

// ---------- weight transpose+convert ----------
__global__ __launch_bounds__(256) void transpose_conv(
    const float* __restrict__ W, u16* __restrict__ Wt, int K, int N)
{
  __shared__ float t[32][33];
  const int kb = blockIdx.y * 32, nb = blockIdx.x * 32;
  const int x = threadIdx.x & 31;
  const int y4 = (threadIdx.x >> 5) * 4;
#pragma unroll
  for (int i = 0; i < 4; ++i)
    t[y4 + i][x] = W[(size_t)(kb + y4 + i) * N + nb + x];
  __syncthreads();
#pragma unroll
  for (int i = 0; i < 4; ++i)
    Wt[(size_t)(nb + y4 + i) * K + kb + x] = f2bf(t[x][y4 + i]);
}

// ---------- elementwise fp32 -> bf16 ----------
__global__ __launch_bounds__(256) void conv_bf16(
    const float* __restrict__ in, u16* __restrict__ out, int n4)
{
  const int idx = blockIdx.x * 256 + threadIdx.x;
  if (idx >= n4) return;
  const float4 v = reinterpret_cast<const float4*>(in)[idx];
  const float f[4] = {v.x, v.y, v.z, v.w};
  uint2 pk;
  pk.x = ((u32)f2bf(f[0])) | (((u32)f2bf(f[1])) << 16);
  pk.y = ((u32)f2bf(f[2])) | (((u32)f2bf(f[3])) << 16);
  reinterpret_cast<uint2*>(out)[idx] = pk;
}

// ---------- MFMA flash self-attention (band mask ADDS +1.0 in-band) ----------
// Softmax tracked in exp2 units: t = raw*0.125*log2e + mask*log2e.
__global__ __launch_bounds__(256, 3) void attn_self_mfma(
    const u16* __restrict__ Q, const u16* __restrict__ K,
    const u16* __restrict__ V, u16* __restrict__ CTX,
    const int* __restrict__ rngp)
{
  const int S = 2048, H = 1024;
  const float SC = 0.125f * 1.44269504f;
  const float MB = 1.44269504f;
  const int qt = blockIdx.x, h = blockIdx.y, b = blockIdx.z;
  const int range = rngp[0];
  const int tid = threadIdx.x;
  const int wave = tid >> 6, lane = tid & 63;
  const int lcol = lane & 15;
  const int lgrp = lane >> 4;

  __shared__ u16 Vt[64][72];
  __shared__ u16 Pb[4][32][72];

  const int qbase = qt * 128 + wave * 32;

  bf16x8 qf[2][2];
#pragma unroll
  for (int rf = 0; rf < 2; ++rf)
#pragma unroll
    for (int dh = 0; dh < 2; ++dh) {
      const int qrow = qbase + rf * 16 + lcol;
      qf[rf][dh] = *(const bf16x8*)&Q[((size_t)(b * S + qrow)) * H + h * 64 + dh * 32 + lgrp * 8];
    }

  f32x4 acc[2][4];
#pragma unroll
  for (int rf = 0; rf < 2; ++rf)
#pragma unroll
    for (int df = 0; df < 4; ++df) {
      acc[rf][df][0] = 0.f; acc[rf][df][1] = 0.f; acc[rf][df][2] = 0.f; acc[rf][df][3] = 0.f;
    }
  float mreg[2][4], lreg[2][4];
#pragma unroll
  for (int rf = 0; rf < 2; ++rf)
#pragma unroll
    for (int reg = 0; reg < 4; ++reg) { mreg[rf][reg] = -1e30f; lreg[rf][reg] = 0.f; }

  for (int c = 0; c < 32; ++c) {
    const int kb = c * 64;
    __syncthreads();
    {
      const u16* vsrc = &V[((size_t)(b * S + kb + lane)) * H + h * 64 + wave * 16];
      uint4 u0 = *(const uint4*)vsrc;
      uint4 u1 = *(const uint4*)(vsrc + 8);
      u16 tmp[16];
      *(uint4*)tmp = u0; *(uint4*)(tmp + 8) = u1;
#pragma unroll
      for (int i = 0; i < 16; ++i) Vt[wave * 16 + i][lane] = tmp[i];
    }
    f32x4 s[2][4];
#pragma unroll
    for (int rf = 0; rf < 2; ++rf)
#pragma unroll
      for (int cf = 0; cf < 4; ++cf) {
        s[rf][cf][0] = 0.f; s[rf][cf][1] = 0.f; s[rf][cf][2] = 0.f; s[rf][cf][3] = 0.f;
      }
#pragma unroll
    for (int dh = 0; dh < 2; ++dh)
#pragma unroll
      for (int cf = 0; cf < 4; ++cf) {
        const int krow = kb + cf * 16 + lcol;
        const bf16x8 kf = *(const bf16x8*)&K[((size_t)(b * S + krow)) * H + h * 64 + dh * 32 + lgrp * 8];
#pragma unroll
        for (int rf = 0; rf < 2; ++rf)
          s[rf][cf] = __builtin_amdgcn_mfma_f32_16x16x32_bf16(qf[rf][dh], kf, s[rf][cf], 0, 0, 0);
      }
#pragma unroll
    for (int rf = 0; rf < 2; ++rf) {
#pragma unroll
      for (int reg = 0; reg < 4; ++reg) {
        const int qrow = qbase + rf * 16 + lgrp * 4 + reg;
        float rmax = -1e30f;
#pragma unroll
        for (int cf = 0; cf < 4; ++cf) {
          const int kcol = kb + cf * 16 + lcol;
          int dd = qrow - kcol; if (dd < 0) dd = -dd;
          const float v = s[rf][cf][reg] * SC + ((dd <= range) ? MB : 0.0f);
          s[rf][cf][reg] = v;
          rmax = fmaxf(rmax, v);
        }
        rmax = fmaxf(rmax, __shfl_xor(rmax, 1));
        rmax = fmaxf(rmax, __shfl_xor(rmax, 2));
        rmax = fmaxf(rmax, __shfl_xor(rmax, 4));
        rmax = fmaxf(rmax, __shfl_xor(rmax, 8));
        const float newm = fmaxf(mreg[rf][reg], rmax);
        const float corr = fast_exp2(mreg[rf][reg] - newm);
        float rsum = 0.f;
#pragma unroll
        for (int cf = 0; cf < 4; ++cf) {
          const float e = fast_exp2(s[rf][cf][reg] - newm);
          s[rf][cf][reg] = e;
          rsum += e;
        }
        rsum += __shfl_xor(rsum, 1);
        rsum += __shfl_xor(rsum, 2);
        rsum += __shfl_xor(rsum, 4);
        rsum += __shfl_xor(rsum, 8);
        lreg[rf][reg] = lreg[rf][reg] * corr + rsum;
        mreg[rf][reg] = newm;
#pragma unroll
        for (int df = 0; df < 4; ++df) acc[rf][df][reg] *= corr;
      }
    }
#pragma unroll
    for (int rf = 0; rf < 2; ++rf)
#pragma unroll
      for (int reg = 0; reg < 4; ++reg)
#pragma unroll
        for (int cf = 0; cf < 4; ++cf)
          Pb[wave][rf * 16 + lgrp * 4 + reg][cf * 16 + lcol] = f2bf(s[rf][cf][reg]);
    __syncthreads();
#pragma unroll
    for (int ks = 0; ks < 2; ++ks) {
      bf16x8 pa[2], vb[4];
#pragma unroll
      for (int rf = 0; rf < 2; ++rf)
        pa[rf] = *(const bf16x8*)&Pb[wave][rf * 16 + lcol][ks * 32 + lgrp * 8];
#pragma unroll
      for (int df = 0; df < 4; ++df)
        vb[df] = *(const bf16x8*)&Vt[df * 16 + lcol][ks * 32 + lgrp * 8];
#pragma unroll
      for (int rf = 0; rf < 2; ++rf)
#pragma unroll
        for (int df = 0; df < 4; ++df)
          acc[rf][df] = __builtin_amdgcn_mfma_f32_16x16x32_bf16(pa[rf], vb[df], acc[rf][df], 0, 0, 0);
    }
  }
#pragma unroll
  for (int rf = 0; rf < 2; ++rf)
#pragma unroll
    for (int reg = 0; reg < 4; ++reg) {
      const int qrow = qbase + rf * 16 + lgrp * 4 + reg;
      const float inv = 1.f / lreg[rf][reg];
#pragma unroll
      for (int df = 0; df < 4; ++df)
        CTX[((size_t)(b * S + qrow)) * H + h * 64 + df * 16 + lcol] =
            f2bf(acc[rf][df][reg] * inv);
    }
}

// ---------- cross-attention (T=50 keys, no mask), bf16 I/O ----------
__global__ __launch_bounds__(256, 1) void attn_cross(
    const u16* __restrict__ Q, const u16* __restrict__ KT,
    const u16* __restrict__ VT, u16* __restrict__ CTX)
{
  const int S = 2048, H = 1024, T = 50;
  const int qt = blockIdx.x, h = blockIdx.y, b = blockIdx.z;
  const int tid = threadIdx.x;
  const int r = tid >> 2, j = tid & 3;
  __shared__ float kt[50][68], vt[50][68];
  __shared__ float qs[64][68];
  __shared__ float ps[64][52];

  for (int idx = tid; idx < T * 8; idx += 256) {
    const int row = idx >> 3, seg = idx & 7;
    float f[8];
    unpack8(reinterpret_cast<const uint4*>(KT + (size_t)row * H + h * 64 + seg * 8)[0], f);
#pragma unroll
    for (int d = 0; d < 8; ++d) kt[row][seg * 8 + d] = f[d];
    unpack8(reinterpret_cast<const uint4*>(VT + (size_t)row * H + h * 64 + seg * 8)[0], f);
#pragma unroll
    for (int d = 0; d < 8; ++d) vt[row][seg * 8 + d] = f[d];
  }
  const int qrow = qt * 64 + r;
  {
    const uint4* qp = reinterpret_cast<const uint4*>(Q + ((size_t)(b * S + qrow) * H + h * 64 + j * 16));
    float f[16];
    unpack8(qp[0], f); unpack8(qp[1], f + 8);
#pragma unroll
    for (int d = 0; d < 16; ++d) qs[r][j * 16 + d] = f[d];
  }
  __syncthreads();

  float sreg[13];
  float rmax = -1e30f;
#pragma unroll
  for (int i = 0; i < 13; ++i) {
    const int k = j + 4 * i;
    float s = -1e30f;
    if (k < T) {
      float acc = 0.f;
      const float4* qr4 = reinterpret_cast<const float4*>(&qs[r][0]);
      const float4* kr4 = reinterpret_cast<const float4*>(&kt[k][0]);
#pragma unroll
      for (int d4 = 0; d4 < 16; ++d4) {
        const float4 qv = qr4[d4], kv = kr4[d4];
        acc += qv.x * kv.x + qv.y * kv.y + qv.z * kv.z + qv.w * kv.w;
      }
      s = acc * (0.125f * 1.44269504f);
    }
    sreg[i] = s;
    rmax = fmaxf(rmax, s);
  }
  rmax = fmaxf(rmax, __shfl_xor(rmax, 1));
  rmax = fmaxf(rmax, __shfl_xor(rmax, 2));
  float rsum = 0.f;
#pragma unroll
  for (int i = 0; i < 13; ++i) {
    const int k = j + 4 * i;
    if (k < T) {
      const float e = fast_exp2(sreg[i] - rmax);
      ps[r][k] = e;
      rsum += e;
    }
  }
  rsum += __shfl_xor(rsum, 1);
  rsum += __shfl_xor(rsum, 2);
  const float inv = 1.f / rsum;

  float acc[16];
#pragma unroll
  for (int d = 0; d < 16; ++d) acc[d] = 0.f;
  for (int k = 0; k < T; ++k) {
    const float p = ps[r][k];
    const float4* vr4 = reinterpret_cast<const float4*>(&vt[k][0]);
#pragma unroll
    for (int q4 = 0; q4 < 4; ++q4) {
      const float4 v = vr4[j * 4 + q4];
      acc[q4 * 4 + 0] = fmaf(p, v.x, acc[q4 * 4 + 0]);
      acc[q4 * 4 + 1] = fmaf(p, v.y, acc[q4 * 4 + 1]);
      acc[q4 * 4 + 2] = fmaf(p, v.z, acc[q4 * 4 + 2]);
      acc[q4 * 4 + 3] = fmaf(p, v.w, acc[q4 * 4 + 3]);
    }
  }
  float o[16];
#pragma unroll
  for (int d = 0; d < 16; ++d) o[d] = acc[d] * inv;
  u16* dst = CTX + ((size_t)(b * S + qrow) * H + h * 64 + j * 16);
  reinterpret_cast<uint4*>(dst)[0] = pack8(o);
  reinterpret_cast<uint4*>(dst)[1] = pack8(o + 8);
}

// ---------- residual + LayerNorm ----------
template<bool CF32, bool RF32, bool OF32>
__global__ __launch_bounds__(256) void ln_res(
    const void* __restrict__ C, const void* __restrict__ Res,
    const float* __restrict__ G, const float* __restrict__ Bb,
    void* __restrict__ Out)
{
  const int H = 1024;
  const int row = blockIdx.x;
  const int tid = threadIdx.x;
  float x[4];
  {
    float c4[4], r4[4];
    if (CF32) {
      const float4 c = reinterpret_cast<const float4*>((const float*)C + (size_t)row * H)[tid];
      c4[0] = c.x; c4[1] = c.y; c4[2] = c.z; c4[3] = c.w;
    } else {
      const uint2 cu = reinterpret_cast<const uint2*>((const u16*)C + (size_t)row * H)[tid];
      c4[0] = __uint_as_float(cu.x << 16); c4[1] = __uint_as_float(cu.x & 0xffff0000u);
      c4[2] = __uint_as_float(cu.y << 16); c4[3] = __uint_as_float(cu.y & 0xffff0000u);
    }
    if (RF32) {
      const float4 rr = reinterpret_cast<const float4*>((const float*)Res + (size_t)row * H)[tid];
      r4[0] = rr.x; r4[1] = rr.y; r4[2] = rr.z; r4[3] = rr.w;
    } else {
      const uint2 ru = reinterpret_cast<const uint2*>((const u16*)Res + (size_t)row * H)[tid];
      r4[0] = __uint_as_float(ru.x << 16); r4[1] = __uint_as_float(ru.x & 0xffff0000u);
      r4[2] = __uint_as_float(ru.y << 16); r4[3] = __uint_as_float(ru.y & 0xffff0000u);
    }
#pragma unroll
    for (int i = 0; i < 4; ++i) x[i] = c4[i] + r4[i];
  }
  float s = x[0] + x[1] + x[2] + x[3];
  float q = x[0] * x[0] + x[1] * x[1] + x[2] * x[2] + x[3] * x[3];
#pragma unroll
  for (int off = 1; off < 64; off <<= 1) {
    s += __shfl_xor(s, off);
    q += __shfl_xor(q, off);
  }
  __shared__ float sb[4][2];
  const int wid = tid >> 6;
  if ((tid & 63) == 0) { sb[wid][0] = s; sb[wid][1] = q; }
  __syncthreads();
  s = sb[0][0] + sb[1][0] + sb[2][0] + sb[3][0];
  q = sb[0][1] + sb[1][1] + sb[2][1] + sb[3][1];
  const float mean = s * (1.f / 1024.f);
  const float var = q * (1.f / 1024.f) - mean * mean;
  const float rstd = rsqrtf(fmaxf(var, 0.f) + 1e-12f);
  const float4 g4 = reinterpret_cast<const float4*>(G)[tid];
  const float4 b4 = reinterpret_cast<const float4*>(Bb)[tid];
  float o[4];
  o[0] = (x[0] - mean) * rstd * g4.x + b4.x;
  o[1] = (x[1] - mean) * rstd * g4.y + b4.y;
  o[2] = (x[2] - mean) * rstd * g4.z + b4.z;
  o[3] = (x[3] - mean) * rstd * g4.w + b4.w;
  if (OF32) {
    reinterpret_cast<float4*>((float*)Out + (size_t)row * H)[tid] =
        make_float4(o[0], o[1], o[2], o[3]);
  } else {
    uint2 pk;
    pk.x = ((u32)f2bf(o[0])) | (((u32)f2bf(o[1])) << 16);
    pk.y = ((u32)f2bf(o[2])) | (((u32)f2bf(o[3])) << 16);
    reinterpret_cast<uint2*>((u16*)Out + (size_t)row * H)[tid] = pk;
  }
}

// ---------- tag gather ----------
__global__ void gather_tags(const float* __restrict__ emb, const int* __restrict__ ids,
                            u16* __restrict__ tags)
{
  const int t = blockIdx.x;
  const int id = ids[t];
  const float4* src = reinterpret_cast<const float4*>(emb + (size_t)id * 1024);
  const float4 a = src[threadIdx.x * 2], b = src[threadIdx.x * 2 + 1];
  const float f[8] = {a.x, a.y, a.z, a.w, b.x, b.y, b.z, b.w};
  reinterpret_cast<uint4*>(tags + (size_t)t * 1024)[threadIdx.x] = pack8(f);
}

// ---------- host ----------
extern "C" void kernel_launch(void* const* d_in, const int* in_sizes, int n_in,
                              void* d_out, int out_size, void* d_ws, size_t ws_size,
                              hipStream_t stream)
{
  const int B = 4, S = 2048, H = 1024, FFN = 4096, T = 50;
  const int M = B * S;

  const bool dict_order = (in_sizes[10] == H * H);
  int i_cqw, i_cqb, i_ckw, i_ckb, i_cvw, i_cvb, i_cow, i_cob;
  int i_slng, i_slnb, i_clng, i_clnb, i_olng, i_olnb;
  int i_iw, i_ib, i_ow, i_ob;
  if (dict_order) {
    i_cqw = 10; i_cqb = 11; i_ckw = 12; i_ckb = 13; i_cvw = 14; i_cvb = 15; i_cow = 16; i_cob = 17;
    i_slng = 18; i_slnb = 19; i_clng = 20; i_clnb = 21; i_olng = 22; i_olnb = 23;
    i_iw = 24; i_ib = 25; i_ow = 26; i_ob = 27;
  } else {
    i_slng = 10; i_slnb = 11;
    i_cqw = 12; i_cqb = 13; i_ckw = 14; i_ckb = 15; i_cvw = 16; i_cvb = 17; i_cow = 18; i_cob = 19;
    i_clng = 20; i_clnb = 21;
    i_iw = 22; i_ib = 23; i_ow = 24; i_ob = 25; i_olng = 26; i_olnb = 27;
  }
  const float* X    = (const float*)d_in[0];
  const float* EMB  = (const float*)d_in[1];
  const float* SQW  = (const float*)d_in[2];
  const float* SQB  = (const float*)d_in[3];
  const float* SKW  = (const float*)d_in[4];
  const float* SKB  = (const float*)d_in[5];
  const float* SVW  = (const float*)d_in[6];
  const float* SVB  = (const float*)d_in[7];
  const float* SOW  = (const float*)d_in[8];
  const float* SOB  = (const float*)d_in[9];
  const float* CQW  = (const float*)d_in[i_cqw];
  const float* CQB  = (const float*)d_in[i_cqb];
  const float* CKW  = (const float*)d_in[i_ckw];
  const float* CKB  = (const float*)d_in[i_ckb];
  const float* CVW  = (const float*)d_in[i_cvw];
  const float* CVB  = (const float*)d_in[i_cvb];
  const float* COW  = (const float*)d_in[i_cow];
  const float* COB  = (const float*)d_in[i_cob];
  const float* SLNG = (const float*)d_in[i_slng];
  const float* SLNB = (const float*)d_in[i_slnb];
  const float* CLNG = (const float*)d_in[i_clng];
  const float* CLNB = (const float*)d_in[i_clnb];
  const float* OLNG = (const float*)d_in[i_olng];
  const float* OLNB = (const float*)d_in[i_olnb];
  const float* IW   = (const float*)d_in[i_iw];
  const float* IB   = (const float*)d_in[i_ib];
  const float* OW   = (const float*)d_in[i_ow];
  const float* OB   = (const float*)d_in[i_ob];
  const int* IDS  = (const int*)d_in[28];
  const int* RNG  = (const int*)d_in[29];

  char* ws = (char*)d_ws;
  u16* tags = (u16*)(ws);
  u16* ktb  = (u16*)(ws + (1 << 17));
  u16* vtb  = (u16*)(ws + (2 << 17));
  char* wreg = ws + (4 << 17);
  const size_t WHH = (size_t)H * H * 2;
  u16* wsq = (u16*)(wreg);
  u16* wsk = (u16*)(wreg + WHH);
  u16* wsv = (u16*)(wreg + 2 * WHH);
  u16* wso = (u16*)(wreg + 3 * WHH);
  u16* wcq = (u16*)(wreg + 4 * WHH);
  u16* wck = (u16*)(wreg + 5 * WHH);
  u16* wcv = (u16*)(wreg + 6 * WHH);
  u16* wco = (u16*)(wreg + 7 * WHH);
  u16* wit = (u16*)(wreg + 8 * WHH);
  u16* wot = (u16*)(wreg + 8 * WHH + (size_t)H * FFN * 2);
  char* slots = wreg + 8 * WHH + 2 * (size_t)H * FFN * 2;
  const size_t SZ = (size_t)M * H * 2;
  u16* s0 = (u16*)(slots);
  u16* s1 = (u16*)(slots + SZ);
  u16* s2 = (u16*)(slots + 2 * SZ);
  u16* s3 = (u16*)(slots + 3 * SZ);
  u16* s4 = (u16*)(slots + 4 * SZ);
  u16* inter = s0;
  float* outp = (float*)d_out;

  const dim3 blk(256);
  const dim3 gsq(H / 128, M / 128);
  const dim3 gt32(H / 32, H / 32);

  conv_bf16<<<dim3((M * H / 4 + 255) / 256), blk, 0, stream>>>(X, s4, M * H / 4);
  transpose_conv<<<gt32, blk, 0, stream>>>(SQW, wsq, H, H);
  transpose_conv<<<gt32, blk, 0, stream>>>(SKW, wsk, H, H);
  transpose_conv<<<gt32, blk, 0, stream>>>(SVW, wsv, H, H);
  transpose_conv<<<gt32, blk, 0, stream>>>(SOW, wso, H, H);
  transpose_conv<<<gt32, blk, 0, stream>>>(CQW, wcq, H, H);
  transpose_conv<<<gt32, blk, 0, stream>>>(CKW, wck, H, H);
  transpose_conv<<<gt32, blk, 0, stream>>>(CVW, wcv, H, H);
  transpose_conv<<<gt32, blk, 0, stream>>>(COW, wco, H, H);
  transpose_conv<<<dim3(FFN / 32, H / 32), blk, 0, stream>>>(IW, wit, H, FFN);
  transpose_conv<<<dim3(H / 32, FFN / 32), blk, 0, stream>>>(OW, wot, FFN, H);

  // --- self-attention block ---
  gemm_mfma_g<<<gsq, blk, 0, stream>>>(s4, wsq, SQB, s0, M, H, H, 0);  // q
  gemm_mfma_g<<<gsq, blk, 0, stream>>>(s4, wsk, SKB, s1, M, H, H, 0);  // k
  gemm_mfma_g<<<gsq, blk, 0, stream>>>(s4, wsv, SVB, s2, M, H, H, 0);  // v
  attn_self_mfma<<<dim3(S / 128, 16, B), blk, 0, stream>>>(s0, s1, s2, s3, RNG);
  gemm_mfma_g<<<gsq, blk, 0, stream>>>(s3, wso, SOB, s0, M, H, H, 0);  // so_out
  ln_res<false, true, false><<<dim3(M), blk, 0, stream>>>(s0, X, SLNG, SLNB, s3);

  // --- cross-attention block ---
  gather_tags<<<dim3(T), dim3(128), 0, stream>>>(EMB, IDS, tags);
  gemm_mfma_k<<<dim3(H / 128, 1), blk, 0, stream>>>(tags, wck, CKB, ktb, T, H, H, 0);
  gemm_mfma_k<<<dim3(H / 128, 1), blk, 0, stream>>>(tags, wcv, CVB, vtb, T, H, H, 0);
  gemm_mfma_g<<<gsq, blk, 0, stream>>>(s3, wcq, CQB, s0, M, H, H, 0);  // cq
  attn_cross<<<dim3(S / 64, 16, B), blk, 0, stream>>>(s0, ktb, vtb, s1);
  gemm_mfma_g<<<gsq, blk, 0, stream>>>(s1, wco, COB, s2, M, H, H, 0);  // co_out
  ln_res<false, false, false><<<dim3(M), blk, 0, stream>>>(s2, s3, CLNG, CLNB, s4);

  // --- FFN block ---
  gemm_mfma_g<<<dim3(FFN / 128, M / 128), blk, 0, stream>>>(s4, wit, IB, inter, M, FFN, H, 1);
  gemm_mfma_g<<<gsq, blk, 0, stream>>>(inter, wot, OB, outp, M, H, FFN, 2);
  ln_res<true, false, true><<<dim3(M), blk, 0, stream>>>(outp, s4, OLNG, OLNB, outp);
}

// Round 7
// 847.864 us; speedup vs baseline: 6.2344x; 1.4727x over previous
//
#include <hip/hip_runtime.h>
#include <cstddef>

using u16 = unsigned short;
using u32 = unsigned int;
typedef short bf16x8 __attribute__((ext_vector_type(8)));
typedef float f32x4 __attribute__((ext_vector_type(4)));

// ---------- bf16 helpers ----------
__device__ __forceinline__ u16 f2bf(float f) {
  u32 x = __float_as_uint(f);
  return (u16)((x + 0x7fffu + ((x >> 16) & 1u)) >> 16);  // RNE
}
__device__ __forceinline__ void unpack8(const uint4 u, float* f) {
  f[0] = __uint_as_float(u.x << 16);
  f[1] = __uint_as_float(u.x & 0xffff0000u);
  f[2] = __uint_as_float(u.y << 16);
  f[3] = __uint_as_float(u.y & 0xffff0000u);
  f[4] = __uint_as_float(u.z << 16);
  f[5] = __uint_as_float(u.z & 0xffff0000u);
  f[6] = __uint_as_float(u.w << 16);
  f[7] = __uint_as_float(u.w & 0xffff0000u);
}
__device__ __forceinline__ uint4 pack8(const float* f) {
  uint4 r;
  r.x = ((u32)f2bf(f[0])) | (((u32)f2bf(f[1])) << 16);
  r.y = ((u32)f2bf(f[2])) | (((u32)f2bf(f[3])) << 16);
  r.z = ((u32)f2bf(f[4])) | (((u32)f2bf(f[5])) << 16);
  r.w = ((u32)f2bf(f[6])) | (((u32)f2bf(f[7])) << 16);
  return r;
}
__device__ __forceinline__ float fast_exp2(float x) {
  float r; asm("v_exp_f32 %0, %1" : "=v"(r) : "v"(x)); return r;
}
__device__ __forceinline__ float gelu_f(float x) {
  const float u = x * (0.7978845608f + 0.0356774081f * x * x);
  const float e = fast_exp2(u * 2.8853900818f);  // exp(2u)
  const float t = 1.f - 2.f / (e + 1.f);
  return 0.5f * x * (1.f + t);
}
__device__ __forceinline__ void gload16(const void* g, void* l) {
  __builtin_amdgcn_global_load_lds(
      (const __attribute__((address_space(1))) u32*)g,
      (__attribute__((address_space(3))) u32*)l, 16, 0, 0);
}

// ---------- MFMA GEMM (M%128==0): C = epi(A[M,K] @ Wt[N,K]^T + bias) ----------
__global__ __launch_bounds__(256, 2) void gemm_mfma_g(
    const u16* __restrict__ A, const u16* __restrict__ Wt,
    const float* __restrict__ bias, void* __restrict__ Cout,
    int M, int N, int K, int outmode)
{
  __shared__ u16 As[128 * 32];
  __shared__ u16 Bs[128 * 32];
  const int tid = threadIdx.x;
  const int wave = tid >> 6, lane = tid & 63;
  const int wr = wave >> 1, wc = wave & 1;
  const int m0 = blockIdx.y * 128, n0 = blockIdx.x * 128;
  const int lrow = lane & 15, lk = lane >> 4;

  const int rr = lane >> 2;
  const int cbl = (lane & 3) * 16;

  f32x4 acc[4][4];
#pragma unroll
  for (int i = 0; i < 4; ++i)
#pragma unroll
    for (int j = 0; j < 4; ++j) {
      acc[i][j][0] = 0.f; acc[i][j][1] = 0.f; acc[i][j][2] = 0.f; acc[i][j][3] = 0.f;
    }

  for (int k0 = 0; k0 < K; k0 += 32) {
    __syncthreads();
#pragma unroll
    for (int i = 0; i < 2; ++i) {
      const int Rloc = wave * 32 + i * 16 + rr;
      const int scb = cbl ^ (((Rloc >> 1) & 3) << 4);
      gload16(A + (size_t)(m0 + Rloc) * K + k0 + (scb >> 1),
              &As[(wave * 32 + i * 16) * 32]);
      gload16(Wt + (size_t)(n0 + Rloc) * K + k0 + (scb >> 1),
              &Bs[(wave * 32 + i * 16) * 32]);
    }
    __syncthreads();

    bf16x8 af[4], bf[4];
#pragma unroll
    for (int i = 0; i < 4; ++i) {
      const int rA = wr * 64 + i * 16 + lrow;
      af[i] = *(const bf16x8*)&As[rA * 32 + ((lk * 16 ^ (((rA >> 1) & 3) << 4)) >> 1)];
      const int rB = wc * 64 + i * 16 + lrow;
      bf[i] = *(const bf16x8*)&Bs[rB * 32 + ((lk * 16 ^ (((rB >> 1) & 3) << 4)) >> 1)];
    }
#pragma unroll
    for (int i = 0; i < 4; ++i)
#pragma unroll
      for (int j = 0; j < 4; ++j)
        acc[i][j] = __builtin_amdgcn_mfma_f32_16x16x32_bf16(af[i], bf[j], acc[i][j], 0, 0, 0);
  }

#pragma unroll
  for (int j = 0; j < 4; ++j) {
    const int gcol = n0 + wc * 64 + j * 16 + lrow;
    const float bj = bias[gcol];
#pragma unroll
    for (int i = 0; i < 4; ++i) {
      const int rbase = m0 + wr * 64 + i * 16 + lk * 4;
#pragma unroll
      for (int reg = 0; reg < 4; ++reg) {
        float c = acc[i][j][reg] + bj;
        if (outmode == 1) c = gelu_f(c);
        if (outmode == 2)
          ((float*)Cout)[(size_t)(rbase + reg) * N + gcol] = c;
        else
          ((u16*)Cout)[(size_t)(rbase + reg) * N + gcol] = f2bf(c);
      }
    }
  }
}

// ---------- MFMA GEMM, guarded (small M, e.g. tags M=50) ----------
__global__ __launch_bounds__(256, 2) void gemm_mfma_k(
    const u16* __restrict__ A, const u16* __restrict__ Wt,
    const float* __restrict__ bias, void* __restrict__ Cout,
    int M, int N, int K, int outmode)
{
  __shared__ u16 As[128][40];
  __shared__ u16 Bs[128][40];
  const int tid = threadIdx.x;
  const int wave = tid >> 6, lane = tid & 63;
  const int wr = wave >> 1, wc = wave & 1;
  const int m0 = blockIdx.y * 128, n0 = blockIdx.x * 128;
  const int lrow = lane & 15, lk = lane >> 4;

  f32x4 acc[4][4];
#pragma unroll
  for (int i = 0; i < 4; ++i)
#pragma unroll
    for (int j = 0; j < 4; ++j) {
      acc[i][j][0] = 0.f; acc[i][j][1] = 0.f; acc[i][j][2] = 0.f; acc[i][j][3] = 0.f;
    }

  const int sr = tid >> 2;
  const int sk = (tid & 3) * 8;
  const bool arow_ok0 = (m0 + sr) < M;
  const bool arow_ok1 = (m0 + sr + 64) < M;

  for (int k0 = 0; k0 < K; k0 += 32) {
    __syncthreads();
    if (arow_ok0)
      *(uint4*)&As[sr][sk] = *(const uint4*)&A[(size_t)(m0 + sr) * K + k0 + sk];
    if (arow_ok1)
      *(uint4*)&As[sr + 64][sk] = *(const uint4*)&A[(size_t)(m0 + sr + 64) * K + k0 + sk];
    *(uint4*)&Bs[sr][sk] = *(const uint4*)&Wt[(size_t)(n0 + sr) * K + k0 + sk];
    *(uint4*)&Bs[sr + 64][sk] = *(const uint4*)&Wt[(size_t)(n0 + sr + 64) * K + k0 + sk];
    __syncthreads();

    bf16x8 af[4], bf[4];
#pragma unroll
    for (int i = 0; i < 4; ++i) {
      af[i] = *(const bf16x8*)&As[wr * 64 + i * 16 + lrow][lk * 8];
      bf[i] = *(const bf16x8*)&Bs[wc * 64 + i * 16 + lrow][lk * 8];
    }
#pragma unroll
    for (int i = 0; i < 4; ++i)
#pragma unroll
      for (int j = 0; j < 4; ++j)
        acc[i][j] = __builtin_amdgcn_mfma_f32_16x16x32_bf16(af[i], bf[j], acc[i][j], 0, 0, 0);
  }

#pragma unroll
  for (int j = 0; j < 4; ++j) {
    const int gcol = n0 + wc * 64 + j * 16 + lrow;
    const float bj = bias[gcol];
#pragma unroll
    for (int i = 0; i < 4; ++i) {
      const int rbase = m0 + wr * 64 + i * 16 + lk * 4;
#pragma unroll
      for (int reg = 0; reg < 4; ++reg) {
        const int grow = rbase + reg;
        if (grow >= M) continue;
        float c = acc[i][j][reg] + bj;
        if (outmode == 1) c = gelu_f(c);
        if (outmode == 2)
          ((float*)Cout)[(size_t)grow * N + gcol] = c;
        else
          ((u16*)Cout)[(size_t)grow * N + gcol] = f2bf(c);
      }
    }
  }
}

// ---------- weight transpose+convert ----------
__global__ __launch_bounds__(256) void transpose_conv(
    const float* __restrict__ W, u16* __restrict__ Wt, int K, int N)
{
  __shared__ float t[32][33];
  const int kb = blockIdx.y * 32, nb = blockIdx.x * 32;
  const int x = threadIdx.x & 31;
  const int y4 = (threadIdx.x >> 5) * 4;
#pragma unroll
  for (int i = 0; i < 4; ++i)
    t[y4 + i][x] = W[(size_t)(kb + y4 + i) * N + nb + x];
  __syncthreads();
#pragma unroll
  for (int i = 0; i < 4; ++i)
    Wt[(size_t)(nb + y4 + i) * K + kb + x] = f2bf(t[x][y4 + i]);
}

// ---------- elementwise fp32 -> bf16 ----------
__global__ __launch_bounds__(256) void conv_bf16(
    const float* __restrict__ in, u16* __restrict__ out, int n4)
{
  const int idx = blockIdx.x * 256 + threadIdx.x;
  if (idx >= n4) return;
  const float4 v = reinterpret_cast<const float4*>(in)[idx];
  const float f[4] = {v.x, v.y, v.z, v.w};
  uint2 pk;
  pk.x = ((u32)f2bf(f[0])) | (((u32)f2bf(f[1])) << 16);
  pk.y = ((u32)f2bf(f[2])) | (((u32)f2bf(f[3])) << 16);
  reinterpret_cast<uint2*>(out)[idx] = pk;
}

// ---------- MFMA flash self-attention (band mask ADDS +1.0 in-band) ----------
__global__ __launch_bounds__(256, 3) void attn_self_mfma(
    const u16* __restrict__ Q, const u16* __restrict__ K,
    const u16* __restrict__ V, u16* __restrict__ CTX,
    const int* __restrict__ rngp)
{
  const int S = 2048, H = 1024;
  const float SC = 0.125f * 1.44269504f;
  const float MB = 1.44269504f;
  const int qt = blockIdx.x, h = blockIdx.y, b = blockIdx.z;
  const int range = rngp[0];
  const int tid = threadIdx.x;
  const int wave = tid >> 6, lane = tid & 63;
  const int lcol = lane & 15;
  const int lgrp = lane >> 4;

  __shared__ u16 Vt[64][72];
  __shared__ u16 Pb[4][32][72];

  const int qbase = qt * 128 + wave * 32;

  bf16x8 qf[2][2];
#pragma unroll
  for (int rf = 0; rf < 2; ++rf)
#pragma unroll
    for (int dh = 0; dh < 2; ++dh) {
      const int qrow = qbase + rf * 16 + lcol;
      qf[rf][dh] = *(const bf16x8*)&Q[((size_t)(b * S + qrow)) * H + h * 64 + dh * 32 + lgrp * 8];
    }

  f32x4 acc[2][4];
#pragma unroll
  for (int rf = 0; rf < 2; ++rf)
#pragma unroll
    for (int df = 0; df < 4; ++df) {
      acc[rf][df][0] = 0.f; acc[rf][df][1] = 0.f; acc[rf][df][2] = 0.f; acc[rf][df][3] = 0.f;
    }
  float mreg[2][4], lreg[2][4];
#pragma unroll
  for (int rf = 0; rf < 2; ++rf)
#pragma unroll
    for (int reg = 0; reg < 4; ++reg) { mreg[rf][reg] = -1e30f; lreg[rf][reg] = 0.f; }

  for (int c = 0; c < 32; ++c) {
    const int kb = c * 64;
    __syncthreads();
    {
      const u16* vsrc = &V[((size_t)(b * S + kb + lane)) * H + h * 64 + wave * 16];
      uint4 u0 = *(const uint4*)vsrc;
      uint4 u1 = *(const uint4*)(vsrc + 8);
      u16 tmp[16];
      *(uint4*)tmp = u0; *(uint4*)(tmp + 8) = u1;
#pragma unroll
      for (int i = 0; i < 16; ++i) Vt[wave * 16 + i][lane] = tmp[i];
    }
    f32x4 s[2][4];
#pragma unroll
    for (int rf = 0; rf < 2; ++rf)
#pragma unroll
      for (int cf = 0; cf < 4; ++cf) {
        s[rf][cf][0] = 0.f; s[rf][cf][1] = 0.f; s[rf][cf][2] = 0.f; s[rf][cf][3] = 0.f;
      }
#pragma unroll
    for (int dh = 0; dh < 2; ++dh)
#pragma unroll
      for (int cf = 0; cf < 4; ++cf) {
        const int krow = kb + cf * 16 + lcol;
        const bf16x8 kf = *(const bf16x8*)&K[((size_t)(b * S + krow)) * H + h * 64 + dh * 32 + lgrp * 8];
#pragma unroll
        for (int rf = 0; rf < 2; ++rf)
          s[rf][cf] = __builtin_amdgcn_mfma_f32_16x16x32_bf16(qf[rf][dh], kf, s[rf][cf], 0, 0, 0);
      }
#pragma unroll
    for (int rf = 0; rf < 2; ++rf) {
#pragma unroll
      for (int reg = 0; reg < 4; ++reg) {
        const int qrow = qbase + rf * 16 + lgrp * 4 + reg;
        float rmax = -1e30f;
#pragma unroll
        for (int cf = 0; cf < 4; ++cf) {
          const int kcol = kb + cf * 16 + lcol;
          int dd = qrow - kcol; if (dd < 0) dd = -dd;
          const float v = s[rf][cf][reg] * SC + ((dd <= range) ? MB : 0.0f);
          s[rf][cf][reg] = v;
          rmax = fmaxf(rmax, v);
        }
        rmax = fmaxf(rmax, __shfl_xor(rmax, 1));
        rmax = fmaxf(rmax, __shfl_xor(rmax, 2));
        rmax = fmaxf(rmax, __shfl_xor(rmax, 4));
        rmax = fmaxf(rmax, __shfl_xor(rmax, 8));
        const float newm = fmaxf(mreg[rf][reg], rmax);
        const float corr = fast_exp2(mreg[rf][reg] - newm);
        float rsum = 0.f;
#pragma unroll
        for (int cf = 0; cf < 4; ++cf) {
          const float e = fast_exp2(s[rf][cf][reg] - newm);
          s[rf][cf][reg] = e;
          rsum += e;
        }
        rsum += __shfl_xor(rsum, 1);
        rsum += __shfl_xor(rsum, 2);
        rsum += __shfl_xor(rsum, 4);
        rsum += __shfl_xor(rsum, 8);
        lreg[rf][reg] = lreg[rf][reg] * corr + rsum;
        mreg[rf][reg] = newm;
#pragma unroll
        for (int df = 0; df < 4; ++df) acc[rf][df][reg] *= corr;
      }
    }
#pragma unroll
    for (int rf = 0; rf < 2; ++rf)
#pragma unroll
      for (int reg = 0; reg < 4; ++reg)
#pragma unroll
        for (int cf = 0; cf < 4; ++cf)
          Pb[wave][rf * 16 + lgrp * 4 + reg][cf * 16 + lcol] = f2bf(s[rf][cf][reg]);
    __syncthreads();
#pragma unroll
    for (int ks = 0; ks < 2; ++ks) {
      bf16x8 pa[2], vb[4];
#pragma unroll
      for (int rf = 0; rf < 2; ++rf)
        pa[rf] = *(const bf16x8*)&Pb[wave][rf * 16 + lcol][ks * 32 + lgrp * 8];
#pragma unroll
      for (int df = 0; df < 4; ++df)
        vb[df] = *(const bf16x8*)&Vt[df * 16 + lcol][ks * 32 + lgrp * 8];
#pragma unroll
      for (int rf = 0; rf < 2; ++rf)
#pragma unroll
        for (int df = 0; df < 4; ++df)
          acc[rf][df] = __builtin_amdgcn_mfma_f32_16x16x32_bf16(pa[rf], vb[df], acc[rf][df], 0, 0, 0);
    }
  }
#pragma unroll
  for (int rf = 0; rf < 2; ++rf)
#pragma unroll
    for (int reg = 0; reg < 4; ++reg) {
      const int qrow = qbase + rf * 16 + lgrp * 4 + reg;
      const float inv = 1.f / lreg[rf][reg];
#pragma unroll
      for (int df = 0; df < 4; ++df)
        CTX[((size_t)(b * S + qrow)) * H + h * 64 + df * 16 + lcol] =
            f2bf(acc[rf][df][reg] * inv);
    }
}

// ---------- MFMA cross-attention: T=50 keys padded to one 64-chunk ----------
// Same fragment structure as attn_self_mfma, single chunk, single-pass softmax.
__global__ __launch_bounds__(256, 3) void attn_cross_mfma(
    const u16* __restrict__ Q, const u16* __restrict__ KT,
    const u16* __restrict__ VT, u16* __restrict__ CTX)
{
  const int S = 2048, H = 1024, T = 50;
  const float SC = 0.125f * 1.44269504f;
  const int qt = blockIdx.x, h = blockIdx.y, b = blockIdx.z;
  const int tid = threadIdx.x;
  const int wave = tid >> 6, lane = tid & 63;
  const int lcol = lane & 15;
  const int lgrp = lane >> 4;

  __shared__ u16 Vt[64][72];
  __shared__ u16 Pb[4][32][72];

  const int qbase = qt * 128 + wave * 32;

  bf16x8 qf[2][2];
#pragma unroll
  for (int rf = 0; rf < 2; ++rf)
#pragma unroll
    for (int dh = 0; dh < 2; ++dh) {
      const int qrow = qbase + rf * 16 + lcol;
      qf[rf][dh] = *(const bf16x8*)&Q[((size_t)(b * S + qrow)) * H + h * 64 + dh * 32 + lgrp * 8];
    }

  // stage Vt[d][k], zero-pad k >= T
  {
    u16 tmp[16];
    if (lane < T) {
      const u16* vsrc = &VT[(size_t)lane * H + h * 64 + wave * 16];
      *(uint4*)tmp = *(const uint4*)vsrc;
      *(uint4*)(tmp + 8) = *(const uint4*)(vsrc + 8);
    } else {
#pragma unroll
      for (int i = 0; i < 16; ++i) tmp[i] = 0;
    }
#pragma unroll
    for (int i = 0; i < 16; ++i) Vt[wave * 16 + i][lane] = tmp[i];
  }

  // QK^T (K rows >= T read in-bounds garbage, masked below)
  f32x4 s[2][4];
#pragma unroll
  for (int rf = 0; rf < 2; ++rf)
#pragma unroll
    for (int cf = 0; cf < 4; ++cf) {
      s[rf][cf][0] = 0.f; s[rf][cf][1] = 0.f; s[rf][cf][2] = 0.f; s[rf][cf][3] = 0.f;
    }
#pragma unroll
  for (int dh = 0; dh < 2; ++dh)
#pragma unroll
    for (int cf = 0; cf < 4; ++cf) {
      const int krow = cf * 16 + lcol;  // 0..63, buffer spans 64 rows
      const bf16x8 kf = *(const bf16x8*)&KT[(size_t)krow * H + h * 64 + dh * 32 + lgrp * 8];
#pragma unroll
      for (int rf = 0; rf < 2; ++rf)
        s[rf][cf] = __builtin_amdgcn_mfma_f32_16x16x32_bf16(qf[rf][dh], kf, s[rf][cf], 0, 0, 0);
    }

  // mask cols >= T, single-pass softmax
  float inv_l[2][4];
#pragma unroll
  for (int rf = 0; rf < 2; ++rf) {
#pragma unroll
    for (int reg = 0; reg < 4; ++reg) {
      float rmax = -1e30f;
#pragma unroll
      for (int cf = 0; cf < 4; ++cf) {
        const int kcol = cf * 16 + lcol;
        const float v = (kcol < T) ? s[rf][cf][reg] * SC : -1e30f;
        s[rf][cf][reg] = v;
        rmax = fmaxf(rmax, v);
      }
      rmax = fmaxf(rmax, __shfl_xor(rmax, 1));
      rmax = fmaxf(rmax, __shfl_xor(rmax, 2));
      rmax = fmaxf(rmax, __shfl_xor(rmax, 4));
      rmax = fmaxf(rmax, __shfl_xor(rmax, 8));
      float rsum = 0.f;
#pragma unroll
      for (int cf = 0; cf < 4; ++cf) {
        const float e = fast_exp2(s[rf][cf][reg] - rmax);
        s[rf][cf][reg] = e;
        rsum += e;
      }
      rsum += __shfl_xor(rsum, 1);
      rsum += __shfl_xor(rsum, 2);
      rsum += __shfl_xor(rsum, 4);
      rsum += __shfl_xor(rsum, 8);
      inv_l[rf][reg] = 1.f / rsum;
    }
  }
#pragma unroll
  for (int rf = 0; rf < 2; ++rf)
#pragma unroll
    for (int reg = 0; reg < 4; ++reg)
#pragma unroll
      for (int cf = 0; cf < 4; ++cf)
        Pb[wave][rf * 16 + lgrp * 4 + reg][cf * 16 + lcol] = f2bf(s[rf][cf][reg]);
  __syncthreads();  // Vt staged by all waves

  f32x4 acc[2][4];
#pragma unroll
  for (int rf = 0; rf < 2; ++rf)
#pragma unroll
    for (int df = 0; df < 4; ++df) {
      acc[rf][df][0] = 0.f; acc[rf][df][1] = 0.f; acc[rf][df][2] = 0.f; acc[rf][df][3] = 0.f;
    }
#pragma unroll
  for (int ks = 0; ks < 2; ++ks) {
    bf16x8 pa[2], vb[4];
#pragma unroll
    for (int rf = 0; rf < 2; ++rf)
      pa[rf] = *(const bf16x8*)&Pb[wave][rf * 16 + lcol][ks * 32 + lgrp * 8];
#pragma unroll
    for (int df = 0; df < 4; ++df)
      vb[df] = *(const bf16x8*)&Vt[df * 16 + lcol][ks * 32 + lgrp * 8];
#pragma unroll
    for (int rf = 0; rf < 2; ++rf)
#pragma unroll
      for (int df = 0; df < 4; ++df)
        acc[rf][df] = __builtin_amdgcn_mfma_f32_16x16x32_bf16(pa[rf], vb[df], acc[rf][df], 0, 0, 0);
  }
#pragma unroll
  for (int rf = 0; rf < 2; ++rf)
#pragma unroll
    for (int reg = 0; reg < 4; ++reg) {
      const int qrow = qbase + rf * 16 + lgrp * 4 + reg;
      const float inv = inv_l[rf][reg];
#pragma unroll
      for (int df = 0; df < 4; ++df)
        CTX[((size_t)(b * S + qrow)) * H + h * 64 + df * 16 + lcol] =
            f2bf(acc[rf][df][reg] * inv);
    }
}

// ---------- residual + LayerNorm ----------
template<bool CF32, bool RF32, bool OF32>
__global__ __launch_bounds__(256) void ln_res(
    const void* __restrict__ C, const void* __restrict__ Res,
    const float* __restrict__ G, const float* __restrict__ Bb,
    void* __restrict__ Out)
{
  const int H = 1024;
  const int row = blockIdx.x;
  const int tid = threadIdx.x;
  float x[4];
  {
    float c4[4], r4[4];
    if (CF32) {
      const float4 c = reinterpret_cast<const float4*>((const float*)C + (size_t)row * H)[tid];
      c4[0] = c.x; c4[1] = c.y; c4[2] = c.z; c4[3] = c.w;
    } else {
      const uint2 cu = reinterpret_cast<const uint2*>((const u16*)C + (size_t)row * H)[tid];
      c4[0] = __uint_as_float(cu.x << 16); c4[1] = __uint_as_float(cu.x & 0xffff0000u);
      c4[2] = __uint_as_float(cu.y << 16); c4[3] = __uint_as_float(cu.y & 0xffff0000u);
    }
    if (RF32) {
      const float4 rr = reinterpret_cast<const float4*>((const float*)Res + (size_t)row * H)[tid];
      r4[0] = rr.x; r4[1] = rr.y; r4[2] = rr.z; r4[3] = rr.w;
    } else {
      const uint2 ru = reinterpret_cast<const uint2*>((const u16*)Res + (size_t)row * H)[tid];
      r4[0] = __uint_as_float(ru.x << 16); r4[1] = __uint_as_float(ru.x & 0xffff0000u);
      r4[2] = __uint_as_float(ru.y << 16); r4[3] = __uint_as_float(ru.y & 0xffff0000u);
    }
#pragma unroll
    for (int i = 0; i < 4; ++i) x[i] = c4[i] + r4[i];
  }
  float s = x[0] + x[1] + x[2] + x[3];
  float q = x[0] * x[0] + x[1] * x[1] + x[2] * x[2] + x[3] * x[3];
#pragma unroll
  for (int off = 1; off < 64; off <<= 1) {
    s += __shfl_xor(s, off);
    q += __shfl_xor(q, off);
  }
  __shared__ float sb[4][2];
  const int wid = tid >> 6;
  if ((tid & 63) == 0) { sb[wid][0] = s; sb[wid][1] = q; }
  __syncthreads();
  s = sb[0][0] + sb[1][0] + sb[2][0] + sb[3][0];
  q = sb[0][1] + sb[1][1] + sb[2][1] + sb[3][1];
  const float mean = s * (1.f / 1024.f);
  const float var = q * (1.f / 1024.f) - mean * mean;
  const float rstd = rsqrtf(fmaxf(var, 0.f) + 1e-12f);
  const float4 g4 = reinterpret_cast<const float4*>(G)[tid];
  const float4 b4 = reinterpret_cast<const float4*>(Bb)[tid];
  float o[4];
  o[0] = (x[0] - mean) * rstd * g4.x + b4.x;
  o[1] = (x[1] - mean) * rstd * g4.y + b4.y;
  o[2] = (x[2] - mean) * rstd * g4.z + b4.z;
  o[3] = (x[3] - mean) * rstd * g4.w + b4.w;
  if (OF32) {
    reinterpret_cast<float4*>((float*)Out + (size_t)row * H)[tid] =
        make_float4(o[0], o[1], o[2], o[3]);
  } else {
    uint2 pk;
    pk.x = ((u32)f2bf(o[0])) | (((u32)f2bf(o[1])) << 16);
    pk.y = ((u32)f2bf(o[2])) | (((u32)f2bf(o[3])) << 16);
    reinterpret_cast<uint2*>((u16*)Out + (size_t)row * H)[tid] = pk;
  }
}

// ---------- tag gather ----------
__global__ void gather_tags(const float* __restrict__ emb, const int* __restrict__ ids,
                            u16* __restrict__ tags)
{
  const int t = blockIdx.x;
  const int id = ids[t];
  const float4* src = reinterpret_cast<const float4*>(emb + (size_t)id * 1024);
  const float4 a = src[threadIdx.x * 2], b = src[threadIdx.x * 2 + 1];
  const float f[8] = {a.x, a.y, a.z, a.w, b.x, b.y, b.z, b.w};
  reinterpret_cast<uint4*>(tags + (size_t)t * 1024)[threadIdx.x] = pack8(f);
}

// ---------- host ----------
extern "C" void kernel_launch(void* const* d_in, const int* in_sizes, int n_in,
                              void* d_out, int out_size, void* d_ws, size_t ws_size,
                              hipStream_t stream)
{
  const int B = 4, S = 2048, H = 1024, FFN = 4096, T = 50;
  const int M = B * S;

  const bool dict_order = (in_sizes[10] == H * H);
  int i_cqw, i_cqb, i_ckw, i_ckb, i_cvw, i_cvb, i_cow, i_cob;
  int i_slng, i_slnb, i_clng, i_clnb, i_olng, i_olnb;
  int i_iw, i_ib, i_ow, i_ob;
  if (dict_order) {
    i_cqw = 10; i_cqb = 11; i_ckw = 12; i_ckb = 13; i_cvw = 14; i_cvb = 15; i_cow = 16; i_cob = 17;
    i_slng = 18; i_slnb = 19; i_clng = 20; i_clnb = 21; i_olng = 22; i_olnb = 23;
    i_iw = 24; i_ib = 25; i_ow = 26; i_ob = 27;
  } else {
    i_slng = 10; i_slnb = 11;
    i_cqw = 12; i_cqb = 13; i_ckw = 14; i_ckb = 15; i_cvw = 16; i_cvb = 17; i_cow = 18; i_cob = 19;
    i_clng = 20; i_clnb = 21;
    i_iw = 22; i_ib = 23; i_ow = 24; i_ob = 25; i_olng = 26; i_olnb = 27;
  }
  const float* X    = (const float*)d_in[0];
  const float* EMB  = (const float*)d_in[1];
  const float* SQW  = (const float*)d_in[2];
  const float* SQB  = (const float*)d_in[3];
  const float* SKW  = (const float*)d_in[4];
  const float* SKB  = (const float*)d_in[5];
  const float* SVW  = (const float*)d_in[6];
  const float* SVB  = (const float*)d_in[7];
  const float* SOW  = (const float*)d_in[8];
  const float* SOB  = (const float*)d_in[9];
  const float* CQW  = (const float*)d_in[i_cqw];
  const float* CQB  = (const float*)d_in[i_cqb];
  const float* CKW  = (const float*)d_in[i_ckw];
  const float* CKB  = (const float*)d_in[i_ckb];
  const float* CVW  = (const float*)d_in[i_cvw];
  const float* CVB  = (const float*)d_in[i_cvb];
  const float* COW  = (const float*)d_in[i_cow];
  const float* COB  = (const float*)d_in[i_cob];
  const float* SLNG = (const float*)d_in[i_slng];
  const float* SLNB = (const float*)d_in[i_slnb];
  const float* CLNG = (const float*)d_in[i_clng];
  const float* CLNB = (const float*)d_in[i_clnb];
  const float* OLNG = (const float*)d_in[i_olng];
  const float* OLNB = (const float*)d_in[i_olnb];
  const float* IW   = (const float*)d_in[i_iw];
  const float* IB   = (const float*)d_in[i_ib];
  const float* OW   = (const float*)d_in[i_ow];
  const float* OB   = (const float*)d_in[i_ob];
  const int* IDS  = (const int*)d_in[28];
  const int* RNG  = (const int*)d_in[29];

  char* ws = (char*)d_ws;
  u16* tags = (u16*)(ws);
  u16* ktb  = (u16*)(ws + (1 << 17));
  u16* vtb  = (u16*)(ws + (2 << 17));
  char* wreg = ws + (4 << 17);
  const size_t WHH = (size_t)H * H * 2;
  u16* wsq = (u16*)(wreg);
  u16* wsk = (u16*)(wreg + WHH);
  u16* wsv = (u16*)(wreg + 2 * WHH);
  u16* wso = (u16*)(wreg + 3 * WHH);
  u16* wcq = (u16*)(wreg + 4 * WHH);
  u16* wck = (u16*)(wreg + 5 * WHH);
  u16* wcv = (u16*)(wreg + 6 * WHH);
  u16* wco = (u16*)(wreg + 7 * WHH);
  u16* wit = (u16*)(wreg + 8 * WHH);
  u16* wot = (u16*)(wreg + 8 * WHH + (size_t)H * FFN * 2);
  char* slots = wreg + 8 * WHH + 2 * (size_t)H * FFN * 2;
  const size_t SZ = (size_t)M * H * 2;
  u16* s0 = (u16*)(slots);
  u16* s1 = (u16*)(slots + SZ);
  u16* s2 = (u16*)(slots + 2 * SZ);
  u16* s3 = (u16*)(slots + 3 * SZ);
  u16* s4 = (u16*)(slots + 4 * SZ);
  u16* inter = s0;
  float* outp = (float*)d_out;

  const dim3 blk(256);
  const dim3 gsq(H / 128, M / 128);
  const dim3 gt32(H / 32, H / 32);

  conv_bf16<<<dim3((M * H / 4 + 255) / 256), blk, 0, stream>>>(X, s4, M * H / 4);
  transpose_conv<<<gt32, blk, 0, stream>>>(SQW, wsq, H, H);
  transpose_conv<<<gt32, blk, 0, stream>>>(SKW, wsk, H, H);
  transpose_conv<<<gt32, blk, 0, stream>>>(SVW, wsv, H, H);
  transpose_conv<<<gt32, blk, 0, stream>>>(SOW, wso, H, H);
  transpose_conv<<<gt32, blk, 0, stream>>>(CQW, wcq, H, H);
  transpose_conv<<<gt32, blk, 0, stream>>>(CKW, wck, H, H);
  transpose_conv<<<gt32, blk, 0, stream>>>(CVW, wcv, H, H);
  transpose_conv<<<gt32, blk, 0, stream>>>(COW, wco, H, H);
  transpose_conv<<<dim3(FFN / 32, H / 32), blk, 0, stream>>>(IW, wit, H, FFN);
  transpose_conv<<<dim3(H / 32, FFN / 32), blk, 0, stream>>>(OW, wot, FFN, H);

  // --- self-attention block ---
  gemm_mfma_g<<<gsq, blk, 0, stream>>>(s4, wsq, SQB, s0, M, H, H, 0);  // q
  gemm_mfma_g<<<gsq, blk, 0, stream>>>(s4, wsk, SKB, s1, M, H, H, 0);  // k
  gemm_mfma_g<<<gsq, blk, 0, stream>>>(s4, wsv, SVB, s2, M, H, H, 0);  // v
  attn_self_mfma<<<dim3(S / 128, 16, B), blk, 0, stream>>>(s0, s1, s2, s3, RNG);
  gemm_mfma_g<<<gsq, blk, 0, stream>>>(s3, wso, SOB, s0, M, H, H, 0);  // so_out
  ln_res<false, true, false><<<dim3(M), blk, 0, stream>>>(s0, X, SLNG, SLNB, s3);

  // --- cross-attention block ---
  gather_tags<<<dim3(T), dim3(128), 0, stream>>>(EMB, IDS, tags);
  gemm_mfma_k<<<dim3(H / 128, 1), blk, 0, stream>>>(tags, wck, CKB, ktb, T, H, H, 0);
  gemm_mfma_k<<<dim3(H / 128, 1), blk, 0, stream>>>(tags, wcv, CVB, vtb, T, H, H, 0);
  gemm_mfma_g<<<gsq, blk, 0, stream>>>(s3, wcq, CQB, s0, M, H, H, 0);  // cq
  attn_cross_mfma<<<dim3(S / 128, 16, B), blk, 0, stream>>>(s0, ktb, vtb, s1);
  gemm_mfma_g<<<gsq, blk, 0, stream>>>(s1, wco, COB, s2, M, H, H, 0);  // co_out
  ln_res<false, false, false><<<dim3(M), blk, 0, stream>>>(s2, s3, CLNG, CLNB, s4);

  // --- FFN block ---
  gemm_mfma_g<<<dim3(FFN / 128, M / 128), blk, 0, stream>>>(s4, wit, IB, inter, M, FFN, H, 1);
  gemm_mfma_g<<<gsq, blk, 0, stream>>>(inter, wot, OB, outp, M, H, FFN, 2);
  ln_res<true, false, true><<<dim3(M), blk, 0, stream>>>(outp, s4, OLNG, OLNB, outp);
}